// Round 1
// baseline (3010.347 us; speedup 1.0000x reference)
//
#include <hip/hip_runtime.h>

typedef __attribute__((ext_vector_type(8))) short short8;
typedef __attribute__((ext_vector_type(4))) float f32x4;
typedef unsigned short ushort_t;

#define E 512
#define NH 8
#define DH 64
#define SS 16
#define BB 128
#define IND 256
#define OUTD 128
#define MEMD 32769
#define NEGV -1000000000.0f
#define EPSV 1e-5f

__device__ __forceinline__ unsigned short f2bf(float f) {
  union { float f; unsigned int u; } v; v.f = f;
  unsigned int u = v.u;
  unsigned int r = u + 0x7fffu + ((u >> 16) & 1u);
  return (unsigned short)(r >> 16);
}
__device__ __forceinline__ float bf2f(unsigned short h) {
  union { unsigned int u; float f; } v; v.u = ((unsigned int)h) << 16;
  return v.f;
}

// ---------------- K0: weight conversion / packing ----------------
__global__ __launch_bounds__(256) void wconvert_kernel(
    const float* __restrict__ ipw, const float* __restrict__ aow,
    const float* __restrict__ ffw, const float* __restrict__ wout,
    const float* __restrict__ win,
    ushort_t* __restrict__ win_bf, ushort_t* __restrict__ wo_bf,
    ushort_t* __restrict__ ff_bf, ushort_t* __restrict__ wout_bf,
    float* __restrict__ winT)
{
  const int tid = blockIdx.x * blockDim.x + threadIdx.x;
  const int stride = gridDim.x * blockDim.x;
  for (int i = tid; i < 2*1536*E; i += stride) win_bf[i] = f2bf(ipw[i]);
  for (int i = tid; i < 2*E*E;    i += stride) wo_bf[i]  = f2bf(aow[i]);
  for (int i = tid; i < 2*E*E;    i += stride) ff_bf[i]  = f2bf(ffw[i]);
  for (int i = tid; i < OUTD*E;   i += stride) wout_bf[i] = f2bf(wout[i]);
  for (int i = tid; i < E*IND;    i += stride) {
    int o = i / IND, k = i % IND;
    winT[k*E + o] = win[i];
  }
}

// ---------------- K1: X = seq @ Win^T + b_in ----------------
__global__ __launch_bounds__(512) void xproj_kernel(
    const float* __restrict__ seq, const float* __restrict__ winT,
    const float* __restrict__ b_in, float* __restrict__ X)
{
  const int b = blockIdx.x;
  const int th = threadIdx.x;
  __shared__ float sq[SS * IND];
  for (int i = th; i < SS * IND; i += 512) {
    int t = i >> 8, k = i & 255;
    sq[i] = seq[((size_t)t * BB + b) * IND + k];
  }
  __syncthreads();
  float acc[SS];
#pragma unroll
  for (int t = 0; t < SS; ++t) acc[t] = 0.f;
  for (int k = 0; k < IND; ++k) {
    float w = winT[k * E + th];
#pragma unroll
    for (int t = 0; t < SS; ++t) acc[t] += sq[t * IND + k] * w;
  }
  float bias = b_in[th];
#pragma unroll
  for (int t = 0; t < SS; ++t)
    X[((size_t)t * BB + b) * E + th] = acc[t] + bias;
}

// ---------------- helpers for main kernel ----------------
__device__ __forceinline__ void gemm_tile4(const ushort_t* __restrict__ Ab,
                                           const ushort_t* __restrict__ W,
                                           ushort_t* __restrict__ dst,
                                           int wave, int g, int c)
{
  const int nb = wave * 64;
  f32x4 o0 = {0.f,0.f,0.f,0.f}, o1 = o0, o2 = o0, o3 = o0;
  const ushort_t* ap = Ab + c*520 + g*8;
  const ushort_t* b0 = W + (size_t)(nb + c)*E + g*8;
  const ushort_t* b1 = b0 + 16*E;
  const ushort_t* b2 = b0 + 32*E;
  const ushort_t* b3 = b0 + 48*E;
#pragma unroll
  for (int kt = 0; kt < 16; ++kt) {
    short8 a = *(const short8*)ap; ap += 32;
    o0 = __builtin_amdgcn_mfma_f32_16x16x32_bf16(a, *(const short8*)b0, o0, 0,0,0); b0 += 32;
    o1 = __builtin_amdgcn_mfma_f32_16x16x32_bf16(a, *(const short8*)b1, o1, 0,0,0); b1 += 32;
    o2 = __builtin_amdgcn_mfma_f32_16x16x32_bf16(a, *(const short8*)b2, o2, 0,0,0); b2 += 32;
    o3 = __builtin_amdgcn_mfma_f32_16x16x32_bf16(a, *(const short8*)b3, o3, 0,0,0); b3 += 32;
  }
#pragma unroll
  for (int r = 0; r < 4; ++r) {
    int rowoff = (4*g + r)*520 + nb + c;
    dst[rowoff +  0] = f2bf(o0[r]);
    dst[rowoff + 16] = f2bf(o1[r]);
    dst[rowoff + 32] = f2bf(o2[r]);
    dst[rowoff + 48] = f2bf(o3[r]);
  }
}

__device__ __forceinline__ void resid_ln(float* hreg, const ushort_t* __restrict__ dbuf,
                                         const float* __restrict__ bias,
                                         const float* __restrict__ sc, const float* __restrict__ bi,
                                         ushort_t* __restrict__ h_bf, int tk, int fb)
{
  float sum = 0.f;
#pragma unroll
  for (int j = 0; j < 16; ++j) {
    float d = bf2f(dbuf[tk*520 + fb + j]) + bias[fb + j];
    hreg[j] += d;
    sum += hreg[j];
  }
  sum += __shfl_xor(sum, 1); sum += __shfl_xor(sum, 2); sum += __shfl_xor(sum, 4);
  sum += __shfl_xor(sum, 8); sum += __shfl_xor(sum, 16);
  float mu = sum * (1.0f/512.0f);
  float s2 = 0.f;
#pragma unroll
  for (int j = 0; j < 16; ++j) { float dd = hreg[j] - mu; s2 += dd*dd; }
  s2 += __shfl_xor(s2, 1); s2 += __shfl_xor(s2, 2); s2 += __shfl_xor(s2, 4);
  s2 += __shfl_xor(s2, 8); s2 += __shfl_xor(s2, 16);
  float rs = rsqrtf(s2 * (1.0f/512.0f) + EPSV);
#pragma unroll
  for (int j = 0; j < 16; ++j) {
    float y = (hreg[j] - mu) * rs * sc[fb + j] + bi[fb + j];
    hreg[j] = y;
    h_bf[tk*520 + fb + j] = f2bf(y);
  }
}

// ---------------- K2: main recurrent encoder, one block per batch elem ----------------
__global__ __launch_bounds__(512, 1) void encoder_kernel(
    const float* __restrict__ Xpre, const float* __restrict__ hstate,
    const ushort_t* __restrict__ win_bf, const ushort_t* __restrict__ wo_bf,
    const ushort_t* __restrict__ ff_bf, const ushort_t* __restrict__ wout_bf,
    const float* __restrict__ ipb, const float* __restrict__ aob,
    const float* __restrict__ l1s, const float* __restrict__ l1b,
    const float* __restrict__ l2s, const float* __restrict__ l2b,
    const float* __restrict__ ffb, const float* __restrict__ bout,
    float* __restrict__ out)
{
  const int b = blockIdx.x;
  const int th = threadIdx.x;
  const int lane = th & 63;
  const int wave = th >> 6;
  const int g = lane >> 4;      // quad within wave
  const int c = lane & 15;      // lane-in-quad (col for C-layout, m for A-layout)
  const int tk = th >> 5;       // token owned for residual/LN (2 tokens per wave)
  const int fb = (th & 31) << 4; // 16-feature chunk owned

  // LDS: 54 KB total
  __shared__ ushort_t h_bf[16*520];     // bf16 mirror of h (16 tokens x 512), padded
  __shared__ ushort_t abuf[16*520];     // attention concat output
  __shared__ ushort_t scratch[9728];    // q/k/vT per 2-head pass, reused as dbuf
  __shared__ ushort_t p_lds[2*16*40];   // softmax P per 2-head pass (K-padded w/ zeros)

  ushort_t* qls = scratch;              // [2][16*72]
  ushort_t* kls = scratch + 2304;       // [2][16*72]
  ushort_t* vls = scratch + 4608;       // [2][64*40]  (vT: [dh][token])
  ushort_t* dbuf = scratch;             // [16*520] (GEMM delta buffer)

  const size_t hsb = (size_t)b * MEMD;
  const int ci0 = (int)hstate[hsb + 32768];

  float hreg[16];
#pragma unroll
  for (int j = 0; j < 16; ++j) {
    float v = hstate[hsb + (size_t)tk*E + fb + j];
    hreg[j] = v;
    h_bf[tk*520 + fb + j] = f2bf(v);
  }
  for (int i = th; i < 2*16*40; i += 512) p_lds[i] = 0;   // zero incl. K-pad cols
  __syncthreads();

  for (int t = 0; t < SS; ++t) {
    const int cic = ci0 + t;
    // ---- stage A: h[ci] <- x_t ----
    if (cic < 16 && tk == cic) {
#pragma unroll
      for (int j = 0; j < 16; ++j) {
        float v = Xpre[((size_t)t*BB + b)*E + fb + j];
        hreg[j] = v;
        h_bf[cic*520 + fb + j] = f2bf(v);
      }
    }
    __syncthreads();

    for (int l = 0; l < 2; ++l) {
      const ushort_t* wi = win_bf + (size_t)l*1536*E;
      const ushort_t* wo = wo_bf + (size_t)l*E*E;
      const ushort_t* wf = ff_bf + (size_t)l*E*E;
      const float* bqkv = ipb + l*1536;

      // ---- attention: 4 passes x 2 heads; 4 waves per head ----
      for (int pass = 0; pass < 4; ++pass) {
        const int hdL = wave >> 2;       // local head (0/1)
        const int hd  = pass*2 + hdL;    // global head
        const int wq  = wave & 3;        // wave-in-head

        // QKV: this wave computes 3 of the head's 12 N-tiles
        int rowb[3];
#pragma unroll
        for (int j = 0; j < 3; ++j) {
          int tid = wq*3 + j;
          rowb[j] = (tid < 4) ? (hd*64 + tid*16)
                  : (tid < 8) ? (512 + hd*64 + (tid-4)*16)
                              : (1024 + hd*64 + (tid-8)*16);
        }
        f32x4 a0 = {0.f,0.f,0.f,0.f}, a1 = a0, a2 = a0;
        {
          const ushort_t* ap = h_bf + c*520 + g*8;
          const ushort_t* bp0 = wi + (size_t)(rowb[0] + c)*E + g*8;
          const ushort_t* bp1 = wi + (size_t)(rowb[1] + c)*E + g*8;
          const ushort_t* bp2 = wi + (size_t)(rowb[2] + c)*E + g*8;
#pragma unroll
          for (int kt = 0; kt < 16; ++kt) {
            short8 a = *(const short8*)ap; ap += 32;
            a0 = __builtin_amdgcn_mfma_f32_16x16x32_bf16(a, *(const short8*)bp0, a0, 0,0,0); bp0 += 32;
            a1 = __builtin_amdgcn_mfma_f32_16x16x32_bf16(a, *(const short8*)bp1, a1, 0,0,0); bp1 += 32;
            a2 = __builtin_amdgcn_mfma_f32_16x16x32_bf16(a, *(const short8*)bp2, a2, 0,0,0); bp2 += 32;
          }
        }
        // zero vT token-pad cols 16..31 (so P-pad zeros never multiply NaN garbage)
        for (int i = th; i < 2048; i += 512) {
          int hh = i >> 10, rr = (i >> 4) & 63, cc = 16 + (i & 15);
          vls[hh*2560 + rr*40 + cc] = 0;
        }
        // scatter C-layout results (+qkv bias) to q/k/vT LDS
        {
          f32x4 av[3] = {a0, a1, a2};
#pragma unroll
          for (int j = 0; j < 3; ++j) {
            int tid = wq*3 + j;
            float bias = bqkv[rowb[j] + c];
#pragma unroll
            for (int r = 0; r < 4; ++r) {
              float val = av[j][r] + bias;
              if (tid < 4)
                qls[hdL*1152 + (4*g + r)*72 + tid*16 + c] = f2bf(val);
              else if (tid < 8)
                kls[hdL*1152 + (4*g + r)*72 + (tid-4)*16 + c] = f2bf(val);
              else
                vls[hdL*2560 + ((tid-8)*16 + c)*40 + (4*g + r)] = f2bf(val);
            }
          }
        }
        __syncthreads();

        // scores + masked softmax (one wave per head)
        if (wq == 0) {
          f32x4 sc = {0.f,0.f,0.f,0.f};
#pragma unroll
          for (int k2 = 0; k2 < 2; ++k2) {
            short8 qa = *(const short8*)&qls[hdL*1152 + c*72 + k2*32 + g*8];
            short8 kb = *(const short8*)&kls[hdL*1152 + c*72 + k2*32 + g*8];
            sc = __builtin_amdgcn_mfma_f32_16x16x32_bf16(qa, kb, sc, 0,0,0);
          }
          float sv[4], mx[4], ex[4], sm[4];
#pragma unroll
          for (int r = 0; r < 4; ++r) {
            int row = 4*g + r;
            bool msk = ((c > cic) || (row > cic)) && (c != 0);
            sv[r] = msk ? NEGV : sc[r]*0.125f;
            mx[r] = sv[r];
          }
#pragma unroll
          for (int r = 0; r < 4; ++r) {
            mx[r] = fmaxf(mx[r], __shfl_xor(mx[r], 1));
            mx[r] = fmaxf(mx[r], __shfl_xor(mx[r], 2));
            mx[r] = fmaxf(mx[r], __shfl_xor(mx[r], 4));
            mx[r] = fmaxf(mx[r], __shfl_xor(mx[r], 8));
          }
#pragma unroll
          for (int r = 0; r < 4; ++r) { ex[r] = __expf(sv[r] - mx[r]); sm[r] = ex[r]; }
#pragma unroll
          for (int r = 0; r < 4; ++r) {
            sm[r] += __shfl_xor(sm[r], 1);
            sm[r] += __shfl_xor(sm[r], 2);
            sm[r] += __shfl_xor(sm[r], 4);
            sm[r] += __shfl_xor(sm[r], 8);
          }
#pragma unroll
          for (int r = 0; r < 4; ++r)
            p_lds[hdL*640 + (4*g + r)*40 + c] = f2bf(ex[r] / sm[r]);
        }
        __syncthreads();

        // PV: each wave does one 16-col tile of the head's 16x64 output
        {
          short8 pa = *(const short8*)&p_lds[hdL*640 + c*40 + g*8];
          short8 vb = *(const short8*)&vls[hdL*2560 + (wq*16 + c)*40 + g*8];
          f32x4 ov = {0.f,0.f,0.f,0.f};
          ov = __builtin_amdgcn_mfma_f32_16x16x32_bf16(pa, vb, ov, 0,0,0);
#pragma unroll
          for (int r = 0; r < 4; ++r)
            abuf[(4*g + r)*520 + hd*64 + wq*16 + c] = f2bf(ov[r]);
        }
        __syncthreads();
      } // pass

      // ---- attention out-proj -> dbuf ----
      gemm_tile4(abuf, wo, dbuf, wave, g, c);
      __syncthreads();
      resid_ln(hreg, dbuf, aob + l*E, l1s + l*E, l1b + l*E, h_bf, tk, fb);
      __syncthreads();
      // ---- FF -> dbuf ----
      gemm_tile4(h_bf, wf, dbuf, wave, g, c);
      __syncthreads();
      resid_ln(hreg, dbuf, ffb + l*E, l2s + l*E, l2b + l*E, h_bf, tk, fb);
      __syncthreads();
    } // layer

    // ---- output projection: out_t = h[ci] @ Wout^T + b_out ----
    {
      const int crow = (cic < 15) ? cic : 15;
      f32x4 oo = {0.f,0.f,0.f,0.f};
      const ushort_t* ap = h_bf + c*520 + g*8;
      const ushort_t* bp = wout_bf + (size_t)(wave*16 + c)*E + g*8;
#pragma unroll
      for (int kt = 0; kt < 16; ++kt) {
        short8 a = *(const short8*)ap; ap += 32;
        oo = __builtin_amdgcn_mfma_f32_16x16x32_bf16(a, *(const short8*)bp, oo, 0,0,0); bp += 32;
      }
      if (g == (crow >> 2)) {
        int r = crow & 3;
        float val = (r == 0) ? oo[0] : (r == 1) ? oo[1] : (r == 2) ? oo[2] : oo[3];
        out[((size_t)t*BB + b)*OUTD + wave*16 + c] = val + bout[wave*16 + c];
      }
    }
    __syncthreads();
  } // t

  // ---- epilogue: new_h = [h_fin, pad, ci+16] ----
  const size_t OB = (size_t)SS * BB * OUTD;
#pragma unroll
  for (int j = 0; j < 16; ++j)
    out[OB + hsb + (size_t)tk*E + fb + j] = hreg[j];
  for (int i = th; i < 48*512; i += 512)
    out[OB + hsb + 8192 + i] = hstate[hsb + 8192 + i];
  if (th == 0) out[OB + hsb + 32768] = (float)(ci0 + SS);
}

// ---------------- launcher ----------------
extern "C" void kernel_launch(void* const* d_in, const int* in_sizes, int n_in,
                              void* d_out, int out_size, void* d_ws, size_t ws_size,
                              hipStream_t stream) {
  const float* seq  = (const float*)d_in[0];
  const float* hs   = (const float*)d_in[1];
  const float* Win  = (const float*)d_in[2];
  const float* b_in = (const float*)d_in[3];
  const float* Wout = (const float*)d_in[4];
  const float* bo   = (const float*)d_in[5];
  const float* ipw  = (const float*)d_in[6];
  const float* ipb  = (const float*)d_in[7];
  const float* aow  = (const float*)d_in[8];
  const float* aob  = (const float*)d_in[9];
  const float* l1s  = (const float*)d_in[10];
  const float* l1b  = (const float*)d_in[11];
  const float* l2s  = (const float*)d_in[12];
  const float* l2b  = (const float*)d_in[13];
  const float* ffw  = (const float*)d_in[14];
  const float* ffb  = (const float*)d_in[15];

  char* ws = (char*)d_ws;
  ushort_t* win_bf  = (ushort_t*)(ws + 0);          // 2*1536*512 bf16 = 3,145,728 B
  ushort_t* wo_bf   = (ushort_t*)(ws + 3145728);    // 2*512*512  bf16 = 1,048,576 B
  ushort_t* ff_bf   = (ushort_t*)(ws + 4194304);    // 2*512*512  bf16 = 1,048,576 B
  ushort_t* wout_bf = (ushort_t*)(ws + 5242880);    // 128*512    bf16 =   131,072 B
  float*    winT    = (float*)   (ws + 5373952);    // 256*512    f32  =   524,288 B
  float*    X       = (float*)   (ws + 5898240);    // 16*128*512 f32  = 4,194,304 B
                                                    // total 10,092,544 B

  wconvert_kernel<<<512, 256, 0, stream>>>(ipw, aow, ffw, Wout, Win,
                                           win_bf, wo_bf, ff_bf, wout_bf, winT);
  xproj_kernel<<<BB, 512, 0, stream>>>(seq, winT, b_in, X);
  encoder_kernel<<<BB, 512, 0, stream>>>(X, hs, win_bf, wo_bf, ff_bf, wout_bf,
                                         ipb, aob, l1s, l1b, l2s, l2b, ffb, bo,
                                         (float*)d_out);
}

// Round 2
// 1133.870 us; speedup vs baseline: 2.6549x; 2.6549x over previous
//
#include <hip/hip_runtime.h>

typedef __attribute__((ext_vector_type(8))) short short8;
typedef __attribute__((ext_vector_type(4))) float f32x4;
typedef unsigned short ushort_t;

#define E 512
#define NH 8
#define DH 64
#define SS 16
#define BB 128
#define IND 256
#define OUTD 128
#define MEMD 32769
#define NEGV -1000000000.0f
#define EPSV 1e-5f

#define MFMA __builtin_amdgcn_mfma_f32_16x16x32_bf16

__device__ __forceinline__ unsigned short f2bf(float f) {
  union { float f; unsigned int u; } v; v.f = f;
  unsigned int u = v.u;
  unsigned int r = u + 0x7fffu + ((u >> 16) & 1u);
  return (unsigned short)(r >> 16);
}
__device__ __forceinline__ float bf2f(unsigned short h) {
  union { unsigned int u; float f; } v; v.u = ((unsigned int)h) << 16;
  return v.f;
}

// ---------------- K0: weight conversion into packed MFMA-tile layout ----------------
// Packed layout: dst[((T*16 + kt)*64 + lane)*8 + j] = W[T*16 + (lane&15)][kt*32 + (lane>>4)*8 + j]
// -> one wave-load per kt is 1KB fully contiguous.
__device__ __forceinline__ void packmat(ushort_t* __restrict__ dst, const float* __restrict__ src,
                                        int n, int tid, int stride) {
  for (int i = tid; i < n; i += stride) {
    int jj = i & 7, lane = (i >> 3) & 63, kt = (i >> 9) & 15, T = i >> 13;
    int row = T * 16 + (lane & 15);
    int col = kt * 32 + (lane >> 4) * 8 + jj;
    dst[i] = f2bf(src[row * 512 + col]);
  }
}

__global__ __launch_bounds__(256) void wconvert_kernel(
    const float* __restrict__ ipw, const float* __restrict__ aow,
    const float* __restrict__ ffw, const float* __restrict__ wout,
    const float* __restrict__ win,
    ushort_t* __restrict__ win_pk, ushort_t* __restrict__ wo_pk,
    ushort_t* __restrict__ ff_pk, ushort_t* __restrict__ wout_pk,
    float* __restrict__ winT)
{
  const int tid = blockIdx.x * blockDim.x + threadIdx.x;
  const int stride = gridDim.x * blockDim.x;
  packmat(win_pk, ipw, 2*1536*E, tid, stride);
  packmat(wo_pk,  aow, 2*E*E,    tid, stride);
  packmat(ff_pk,  ffw, 2*E*E,    tid, stride);
  packmat(wout_pk, wout, OUTD*E, tid, stride);
  for (int i = tid; i < E*IND; i += stride) {
    int o = i / IND, k = i % IND;
    winT[k*E + o] = win[i];
  }
}

// ---------------- K1: X = seq @ Win^T + b_in ----------------
__global__ __launch_bounds__(512) void xproj_kernel(
    const float* __restrict__ seq, const float* __restrict__ winT,
    const float* __restrict__ b_in, float* __restrict__ X)
{
  const int b = blockIdx.x;
  const int th = threadIdx.x;
  __shared__ float sq[SS * IND];
  for (int i = th; i < SS * IND; i += 512) {
    int t = i >> 8, k = i & 255;
    sq[i] = seq[((size_t)t * BB + b) * IND + k];
  }
  __syncthreads();
  float acc[SS];
#pragma unroll
  for (int t = 0; t < SS; ++t) acc[t] = 0.f;
  for (int k = 0; k < IND; ++k) {
    float w = winT[k * E + th];
#pragma unroll
    for (int t = 0; t < SS; ++t) acc[t] += sq[t * IND + k] * w;
  }
  float bias = b_in[th];
#pragma unroll
  for (int t = 0; t < SS; ++t)
    X[((size_t)t * BB + b) * E + th] = acc[t] + bias;
}

// ---------------- GEMM helpers (packed B, ping-pong prefetch) ----------------
template<int NKT>
__device__ __forceinline__ void gemm_2tile(const ushort_t* __restrict__ Ab,
                                           const ushort_t* __restrict__ B0,
                                           const ushort_t* __restrict__ B1,
                                           f32x4& acc0, f32x4& acc1)
{
  short8 b00 = *(const short8*)(B0);
  short8 b10 = *(const short8*)(B1);
  short8 b01 = *(const short8*)(B0 + 512);
  short8 b11 = *(const short8*)(B1 + 512);
#pragma unroll
  for (int k2 = 0; k2 < NKT/2; ++k2) {
    short8 a = *(const short8*)(Ab + (2*k2)*32);
    acc0 = MFMA(a, b00, acc0, 0,0,0);
    acc1 = MFMA(a, b10, acc1, 0,0,0);
    if (k2 < NKT/2 - 1) {
      b00 = *(const short8*)(B0 + (2*k2+2)*512);
      b10 = *(const short8*)(B1 + (2*k2+2)*512);
    }
    short8 a2 = *(const short8*)(Ab + (2*k2+1)*32);
    acc0 = MFMA(a2, b01, acc0, 0,0,0);
    acc1 = MFMA(a2, b11, acc1, 0,0,0);
    if (k2 < NKT/2 - 1) {
      b01 = *(const short8*)(B0 + (2*k2+3)*512);
      b11 = *(const short8*)(B1 + (2*k2+3)*512);
    }
  }
}

// ---------------- K2: main recurrent encoder, one block (1024 thr) per batch elem ----------------
__global__ __launch_bounds__(1024, 4) void encoder_kernel(
    const float* __restrict__ Xpre, const float* __restrict__ hstate,
    const ushort_t* __restrict__ win_pk, const ushort_t* __restrict__ wo_pk,
    const ushort_t* __restrict__ ff_pk, const ushort_t* __restrict__ wout_pk,
    const float* __restrict__ ipb, const float* __restrict__ aob,
    const float* __restrict__ l1s, const float* __restrict__ l1b,
    const float* __restrict__ l2s, const float* __restrict__ l2b,
    const float* __restrict__ ffb, const float* __restrict__ bout,
    float* __restrict__ out)
{
  const int b = blockIdx.x;
  const int th = threadIdx.x;
  const int lane = th & 63;
  const int w = th >> 6;         // wave 0..15
  const int g = lane >> 4;       // quad
  const int c = lane & 15;       // lane-in-quad
  const int fb = (lane) << 3;    // 8-feature chunk for LN (lane*8)

  // LDS (static, 60,672 B)
  __shared__ ushort_t h_bf[16*520];   // h (16 tok x 512), bf16, padded
  __shared__ ushort_t qk[9216];       // q[4][16][72], k[4][16][72]; abuf_p(16x264) aliases
  __shared__ ushort_t vbuf[10240];    // vT[4][64][40]; dbuf(16x520) aliases
  __shared__ ushort_t p_lds[2560];    // P[4][16][40], cols 16..31 kept zero

  ushort_t* q_lds = qk;
  ushort_t* k_lds = qk + 4608;
  ushort_t* abuf_p = qk;              // alias (q/k dead when written)
  ushort_t* dbuf = vbuf;              // alias (vT dead when written)

  const size_t hsb = (size_t)b * MEMD;
  const int ci0 = (int)hstate[hsb + 32768];

  float hreg[8];
#pragma unroll
  for (int j = 0; j < 8; ++j) {
    float v = hstate[hsb + (size_t)w*E + fb + j];
    hreg[j] = v;
    h_bf[w*520 + fb + j] = f2bf(v);
  }
  for (int i = th; i < 2560; i += 1024) p_lds[i] = 0;
  __syncthreads();

#pragma unroll 1
  for (int t = 0; t < SS; ++t) {
    const int cic = ci0 + t;
    // ---- stage A: h[cic] <- x_t (wave cic owns the row) ----
    if (cic < 16 && w == cic) {
#pragma unroll
      for (int j = 0; j < 8; ++j) {
        float v = Xpre[((size_t)t*BB + b)*E + fb + j];
        hreg[j] = v;
        h_bf[w*520 + fb + j] = f2bf(v);
      }
    }
    __syncthreads();

#pragma unroll 1
    for (int l = 0; l < 2; ++l) {
      const ushort_t* wi = win_pk + (size_t)l*1536*E;
      const ushort_t* wo = wo_pk + (size_t)l*E*E;
      const ushort_t* wf = ff_pk + (size_t)l*E*E;
      const float* bqkv = ipb + l*1536;

      f32x4 oacc0 = {0.f,0.f,0.f,0.f}, oacc1 = oacc0;

#pragma unroll 1
      for (int pass = 0; pass < 2; ++pass) {
        const int hl = w >> 2;          // local head for scatter
        const int dhb = (w & 3) * 16;   // dh base within head

        // ---- QKV: each wave 1 q-tile + 1 k-tile + 1 v-tile, K=512 ----
        {
          const ushort_t* A = h_bf + c*520 + g*8;
          const int Tq = pass*16 + w;
          const ushort_t* pq = wi + ((size_t)Tq*16)*512 + lane*8;
          const ushort_t* pk = wi + ((size_t)(32 + Tq)*16)*512 + lane*8;
          const ushort_t* pv = wi + ((size_t)(64 + Tq)*16)*512 + lane*8;
          f32x4 aq = {0.f,0.f,0.f,0.f}, ak = aq, av = aq;
          short8 bq0 = *(const short8*)(pq);
          short8 bk0 = *(const short8*)(pk);
          short8 bv0 = *(const short8*)(pv);
          short8 bq1 = *(const short8*)(pq + 512);
          short8 bk1 = *(const short8*)(pk + 512);
          short8 bv1 = *(const short8*)(pv + 512);
#pragma unroll
          for (int k2 = 0; k2 < 8; ++k2) {
            short8 a0 = *(const short8*)(A + (2*k2)*32);
            aq = MFMA(a0, bq0, aq, 0,0,0);
            ak = MFMA(a0, bk0, ak, 0,0,0);
            av = MFMA(a0, bv0, av, 0,0,0);
            if (k2 < 7) {
              bq0 = *(const short8*)(pq + (2*k2+2)*512);
              bk0 = *(const short8*)(pk + (2*k2+2)*512);
              bv0 = *(const short8*)(pv + (2*k2+2)*512);
            }
            short8 a1 = *(const short8*)(A + (2*k2+1)*32);
            aq = MFMA(a1, bq1, aq, 0,0,0);
            ak = MFMA(a1, bk1, ak, 0,0,0);
            av = MFMA(a1, bv1, av, 0,0,0);
            if (k2 < 7) {
              bq1 = *(const short8*)(pq + (2*k2+3)*512);
              bk1 = *(const short8*)(pk + (2*k2+3)*512);
              bv1 = *(const short8*)(pv + (2*k2+3)*512);
            }
          }
          // zero vT token-pad cols 16..31
          for (int i = th; i < 4096; i += 1024) {
            int h2 = i >> 10, dh = (i >> 4) & 63, t16 = i & 15;
            vbuf[h2*2560 + dh*40 + 16 + t16] = 0;
          }
          // scatter (+bias) to q/k/vT
          const float biq = bqkv[pass*256 + w*16 + c];
          const float bik = bqkv[512 + pass*256 + w*16 + c];
          const float biv = bqkv[1024 + pass*256 + w*16 + c];
#pragma unroll
          for (int r = 0; r < 4; ++r) {
            int tok = 4*g + r;
            q_lds[hl*1152 + tok*72 + dhb + c] = f2bf(aq[r] + biq);
            k_lds[hl*1152 + tok*72 + dhb + c] = f2bf(ak[r] + bik);
            vbuf[hl*2560 + (dhb + c)*40 + tok] = f2bf(av[r] + biv);
          }
        }
        __syncthreads();

        // ---- scores + masked softmax: waves 0..3, one head each ----
        if (w < 4) {
          f32x4 sc = {0.f,0.f,0.f,0.f};
#pragma unroll
          for (int k2 = 0; k2 < 2; ++k2) {
            short8 qa = *(const short8*)&q_lds[w*1152 + c*72 + k2*32 + g*8];
            short8 kb = *(const short8*)&k_lds[w*1152 + c*72 + k2*32 + g*8];
            sc = MFMA(qa, kb, sc, 0,0,0);
          }
          float sv[4], mx[4], ex[4], sm[4];
#pragma unroll
          for (int r = 0; r < 4; ++r) {
            int row = 4*g + r;
            bool msk = ((c > cic) || (row > cic)) && (c != 0);
            sv[r] = msk ? NEGV : sc[r]*0.125f;
            mx[r] = sv[r];
          }
#pragma unroll
          for (int r = 0; r < 4; ++r) {
            mx[r] = fmaxf(mx[r], __shfl_xor(mx[r], 1));
            mx[r] = fmaxf(mx[r], __shfl_xor(mx[r], 2));
            mx[r] = fmaxf(mx[r], __shfl_xor(mx[r], 4));
            mx[r] = fmaxf(mx[r], __shfl_xor(mx[r], 8));
          }
#pragma unroll
          for (int r = 0; r < 4; ++r) { ex[r] = __expf(sv[r] - mx[r]); sm[r] = ex[r]; }
#pragma unroll
          for (int r = 0; r < 4; ++r) {
            sm[r] += __shfl_xor(sm[r], 1);
            sm[r] += __shfl_xor(sm[r], 2);
            sm[r] += __shfl_xor(sm[r], 4);
            sm[r] += __shfl_xor(sm[r], 8);
          }
#pragma unroll
          for (int r = 0; r < 4; ++r)
            p_lds[w*640 + (4*g + r)*40 + c] = f2bf(ex[r] / sm[r]);
        }
        __syncthreads();

        // ---- PV: 16 tiles (4 heads x 4 col-tiles), one per wave ----
        {
          const int hl2 = w >> 2, ct = w & 3;
          short8 pa = *(const short8*)&p_lds[hl2*640 + c*40 + g*8];
          short8 vb = *(const short8*)&vbuf[hl2*2560 + (ct*16 + c)*40 + g*8];
          f32x4 ov = {0.f,0.f,0.f,0.f};
          ov = MFMA(pa, vb, ov, 0,0,0);
#pragma unroll
          for (int r = 0; r < 4; ++r)
            abuf_p[(4*g + r)*264 + hl2*64 + ct*16 + c] = f2bf(ov[r]);
        }
        __syncthreads();

        // ---- attention out-proj partial: K=256 (this pass's features) ----
        {
          const ushort_t* A = abuf_p + c*264 + g*8;
          const ushort_t* B0 = wo + ((size_t)w*16 + pass*8)*512 + lane*8;
          const ushort_t* B1 = wo + ((size_t)(w+16)*16 + pass*8)*512 + lane*8;
          gemm_2tile<8>(A, B0, B1, oacc0, oacc1);
        }
        __syncthreads();
      } // pass

      // ---- write out-proj result, residual + LN1 ----
#pragma unroll
      for (int r = 0; r < 4; ++r) {
        dbuf[(4*g + r)*520 + w*16 + c]       = f2bf(oacc0[r]);
        dbuf[(4*g + r)*520 + 256 + w*16 + c] = f2bf(oacc1[r]);
      }
      __syncthreads();
      {
        const float* bias = aob + l*E;
        const float* sc1 = l1s + l*E; const float* bi1 = l1b + l*E;
        float sum = 0.f;
#pragma unroll
        for (int j = 0; j < 8; ++j) {
          float d = bf2f(dbuf[w*520 + fb + j]) + bias[fb + j];
          hreg[j] += d; sum += hreg[j];
        }
        sum += __shfl_xor(sum, 1); sum += __shfl_xor(sum, 2); sum += __shfl_xor(sum, 4);
        sum += __shfl_xor(sum, 8); sum += __shfl_xor(sum, 16); sum += __shfl_xor(sum, 32);
        float mu = sum * (1.0f/512.0f);
        float s2 = 0.f;
#pragma unroll
        for (int j = 0; j < 8; ++j) { float dd = hreg[j] - mu; s2 += dd*dd; }
        s2 += __shfl_xor(s2, 1); s2 += __shfl_xor(s2, 2); s2 += __shfl_xor(s2, 4);
        s2 += __shfl_xor(s2, 8); s2 += __shfl_xor(s2, 16); s2 += __shfl_xor(s2, 32);
        float rs = rsqrtf(s2 * (1.0f/512.0f) + EPSV);
#pragma unroll
        for (int j = 0; j < 8; ++j) {
          float y = (hreg[j] - mu) * rs * sc1[fb + j] + bi1[fb + j];
          hreg[j] = y;
          h_bf[w*520 + fb + j] = f2bf(y);
        }
      }
      __syncthreads();

      // ---- FF GEMM: 2 tiles per wave, K=512 ----
      {
        f32x4 f0 = {0.f,0.f,0.f,0.f}, f1 = f0;
        const ushort_t* A = h_bf + c*520 + g*8;
        const ushort_t* B0 = wf + ((size_t)w*16)*512 + lane*8;
        const ushort_t* B1 = wf + ((size_t)(w+16)*16)*512 + lane*8;
        gemm_2tile<16>(A, B0, B1, f0, f1);
#pragma unroll
        for (int r = 0; r < 4; ++r) {
          dbuf[(4*g + r)*520 + w*16 + c]       = f2bf(f0[r]);
          dbuf[(4*g + r)*520 + 256 + w*16 + c] = f2bf(f1[r]);
        }
      }
      __syncthreads();
      {
        const float* bias = ffb + l*E;
        const float* sc2 = l2s + l*E; const float* bi2 = l2b + l*E;
        float sum = 0.f;
#pragma unroll
        for (int j = 0; j < 8; ++j) {
          float d = bf2f(dbuf[w*520 + fb + j]) + bias[fb + j];
          hreg[j] += d; sum += hreg[j];
        }
        sum += __shfl_xor(sum, 1); sum += __shfl_xor(sum, 2); sum += __shfl_xor(sum, 4);
        sum += __shfl_xor(sum, 8); sum += __shfl_xor(sum, 16); sum += __shfl_xor(sum, 32);
        float mu = sum * (1.0f/512.0f);
        float s2 = 0.f;
#pragma unroll
        for (int j = 0; j < 8; ++j) { float dd = hreg[j] - mu; s2 += dd*dd; }
        s2 += __shfl_xor(s2, 1); s2 += __shfl_xor(s2, 2); s2 += __shfl_xor(s2, 4);
        s2 += __shfl_xor(s2, 8); s2 += __shfl_xor(s2, 16); s2 += __shfl_xor(s2, 32);
        float rs = rsqrtf(s2 * (1.0f/512.0f) + EPSV);
#pragma unroll
        for (int j = 0; j < 8; ++j) {
          float y = (hreg[j] - mu) * rs * sc2[fb + j] + bi2[fb + j];
          hreg[j] = y;
          h_bf[w*520 + fb + j] = f2bf(y);
        }
      }
      __syncthreads();
    } // layer

    // ---- output projection: out_t = h[cic] @ Wout^T + b_out (waves 0..7) ----
    if (w < 8) {
      const int crow = (cic < 15) ? cic : 15;
      f32x4 oo = {0.f,0.f,0.f,0.f};
      const ushort_t* A = h_bf + c*520 + g*8;
      const ushort_t* B0 = wout_pk + ((size_t)w*16)*512 + lane*8;
      short8 b0 = *(const short8*)(B0);
      short8 b1 = *(const short8*)(B0 + 512);
      short8 b2 = *(const short8*)(B0 + 1024);
      short8 b3 = *(const short8*)(B0 + 1536);
#pragma unroll
      for (int k4 = 0; k4 < 4; ++k4) {
        short8 a0 = *(const short8*)(A + (4*k4)*32);
        oo = MFMA(a0, b0, oo, 0,0,0);
        if (k4 < 3) b0 = *(const short8*)(B0 + (4*k4+4)*512);
        short8 a1 = *(const short8*)(A + (4*k4+1)*32);
        oo = MFMA(a1, b1, oo, 0,0,0);
        if (k4 < 3) b1 = *(const short8*)(B0 + (4*k4+5)*512);
        short8 a2 = *(const short8*)(A + (4*k4+2)*32);
        oo = MFMA(a2, b2, oo, 0,0,0);
        if (k4 < 3) b2 = *(const short8*)(B0 + (4*k4+6)*512);
        short8 a3 = *(const short8*)(A + (4*k4+3)*32);
        oo = MFMA(a3, b3, oo, 0,0,0);
        if (k4 < 3) b3 = *(const short8*)(B0 + (4*k4+7)*512);
      }
      if (g == (crow >> 2)) {
        int r = crow & 3;
        float val = (r == 0) ? oo[0] : (r == 1) ? oo[1] : (r == 2) ? oo[2] : oo[3];
        out[((size_t)t*BB + b)*OUTD + w*16 + c] = val + bout[w*16 + c];
      }
    }
    __syncthreads();
  } // t

  // ---- epilogue: new_h = [h_fin, pad, ci+16] ----
  const size_t OB = (size_t)SS * BB * OUTD;
#pragma unroll
  for (int j = 0; j < 8; ++j)
    out[OB + hsb + (size_t)w*E + fb + j] = hreg[j];
  for (int i = th; i < 48*512; i += 1024)
    out[OB + hsb + 8192 + i] = hstate[hsb + 8192 + i];
  if (th == 0) out[OB + hsb + 32768] = (float)(ci0 + SS);
}

// ---------------- launcher ----------------
extern "C" void kernel_launch(void* const* d_in, const int* in_sizes, int n_in,
                              void* d_out, int out_size, void* d_ws, size_t ws_size,
                              hipStream_t stream) {
  const float* seq  = (const float*)d_in[0];
  const float* hs   = (const float*)d_in[1];
  const float* Win  = (const float*)d_in[2];
  const float* b_in = (const float*)d_in[3];
  const float* Wout = (const float*)d_in[4];
  const float* bo   = (const float*)d_in[5];
  const float* ipw  = (const float*)d_in[6];
  const float* ipb  = (const float*)d_in[7];
  const float* aow  = (const float*)d_in[8];
  const float* aob  = (const float*)d_in[9];
  const float* l1s  = (const float*)d_in[10];
  const float* l1b  = (const float*)d_in[11];
  const float* l2s  = (const float*)d_in[12];
  const float* l2b  = (const float*)d_in[13];
  const float* ffw  = (const float*)d_in[14];
  const float* ffb  = (const float*)d_in[15];

  char* ws = (char*)d_ws;
  ushort_t* win_pk  = (ushort_t*)(ws + 0);          // 2*1536*512 bf16 = 3,145,728 B
  ushort_t* wo_pk   = (ushort_t*)(ws + 3145728);    // 2*512*512  bf16 = 1,048,576 B
  ushort_t* ff_pk   = (ushort_t*)(ws + 4194304);    // 2*512*512  bf16 = 1,048,576 B
  ushort_t* wout_pk = (ushort_t*)(ws + 5242880);    // 128*512    bf16 =   131,072 B
  float*    winT    = (float*)   (ws + 5373952);    // 256*512    f32  =   524,288 B
  float*    X       = (float*)   (ws + 5898240);    // 16*128*512 f32  = 4,194,304 B

  wconvert_kernel<<<512, 256, 0, stream>>>(ipw, aow, ffw, Wout, Win,
                                           win_pk, wo_pk, ff_pk, wout_pk, winT);
  xproj_kernel<<<BB, 512, 0, stream>>>(seq, winT, b_in, X);
  encoder_kernel<<<BB, 1024, 0, stream>>>(X, hs, win_pk, wo_pk, ff_pk, wout_pk,
                                          ipb, aob, l1s, l1b, l2s, l2b, ffb, bo,
                                          (float*)d_out);
}

// Round 3
// 1126.214 us; speedup vs baseline: 2.6730x; 1.0068x over previous
//
#include <hip/hip_runtime.h>

typedef __attribute__((ext_vector_type(8))) short short8;
typedef __attribute__((ext_vector_type(4))) float f32x4;
typedef unsigned short ushort_t;

#define E 512
#define NH 8
#define DH 64
#define SS 16
#define BB 128
#define IND 256
#define OUTD 128
#define MEMD 32769
#define NEGV -1000000000.0f
#define EPSV 1e-5f

#define MFMA __builtin_amdgcn_mfma_f32_16x16x32_bf16

// LDS-visibility-only barrier: does NOT drain vmcnt, so global weight loads
// issued before it stay in flight across phases (CK block_sync_lds idiom).
__device__ __forceinline__ void bar_lds() {
  asm volatile("s_waitcnt lgkmcnt(0)\ns_barrier" ::: "memory");
}

__device__ __forceinline__ unsigned short f2bf(float f) {
  union { float f; unsigned int u; } v; v.f = f;
  unsigned int u = v.u;
  unsigned int r = u + 0x7fffu + ((u >> 16) & 1u);
  return (unsigned short)(r >> 16);
}
__device__ __forceinline__ float bf2f(unsigned short h) {
  union { unsigned int u; float f; } v; v.u = ((unsigned int)h) << 16;
  return v.f;
}

// ---------------- K0: weight conversion into packed MFMA-tile layout ----------------
// dst[((T*16 + kt)*64 + lane)*8 + j] = W[T*16 + (lane&15)][kt*32 + (lane>>4)*8 + j]
__device__ __forceinline__ void packmat(ushort_t* __restrict__ dst, const float* __restrict__ src,
                                        int n, int tid, int stride) {
  for (int i = tid; i < n; i += stride) {
    int jj = i & 7, lane = (i >> 3) & 63, kt = (i >> 9) & 15, T = i >> 13;
    int row = T * 16 + (lane & 15);
    int col = kt * 32 + (lane >> 4) * 8 + jj;
    dst[i] = f2bf(src[row * 512 + col]);
  }
}

__global__ __launch_bounds__(256) void wconvert_kernel(
    const float* __restrict__ ipw, const float* __restrict__ aow,
    const float* __restrict__ ffw, const float* __restrict__ wout,
    const float* __restrict__ win,
    ushort_t* __restrict__ win_pk, ushort_t* __restrict__ wo_pk,
    ushort_t* __restrict__ ff_pk, ushort_t* __restrict__ wout_pk,
    float* __restrict__ winT)
{
  const int tid = blockIdx.x * blockDim.x + threadIdx.x;
  const int stride = gridDim.x * blockDim.x;
  packmat(win_pk, ipw, 2*1536*E, tid, stride);
  packmat(wo_pk,  aow, 2*E*E,    tid, stride);
  packmat(ff_pk,  ffw, 2*E*E,    tid, stride);
  packmat(wout_pk, wout, OUTD*E, tid, stride);
  for (int i = tid; i < E*IND; i += stride) {
    int o = i / IND, k = i % IND;
    winT[k*E + o] = win[i];
  }
}

// ---------------- K1: X = seq @ Win^T + b_in ----------------
__global__ __launch_bounds__(512) void xproj_kernel(
    const float* __restrict__ seq, const float* __restrict__ winT,
    const float* __restrict__ b_in, float* __restrict__ X)
{
  const int b = blockIdx.x;
  const int th = threadIdx.x;
  __shared__ float sq[SS * IND];
  for (int i = th; i < SS * IND; i += 512) {
    int t = i >> 8, k = i & 255;
    sq[i] = seq[((size_t)t * BB + b) * IND + k];
  }
  __syncthreads();
  float acc[SS];
#pragma unroll
  for (int t = 0; t < SS; ++t) acc[t] = 0.f;
  for (int k = 0; k < IND; ++k) {
    float w = winT[k * E + th];
#pragma unroll
    for (int t = 0; t < SS; ++t) acc[t] += sq[t * IND + k] * w;
  }
  float bias = b_in[th];
#pragma unroll
  for (int t = 0; t < SS; ++t)
    X[((size_t)t * BB + b) * E + th] = acc[t] + bias;
}

// ---------------- K2: main recurrent encoder, one block (1024 thr) per batch elem ----------------
__global__ __launch_bounds__(1024, 4) void encoder_kernel(
    const float* __restrict__ Xpre, const float* __restrict__ hstate,
    const ushort_t* __restrict__ win_pk, const ushort_t* __restrict__ wo_pk,
    const ushort_t* __restrict__ ff_pk, const ushort_t* __restrict__ wout_pk,
    const float* __restrict__ ipb, const float* __restrict__ aob,
    const float* __restrict__ l1s, const float* __restrict__ l1b,
    const float* __restrict__ l2s, const float* __restrict__ l2b,
    const float* __restrict__ ffb, const float* __restrict__ bout,
    float* __restrict__ out)
{
  const int b = blockIdx.x;
  const int th = threadIdx.x;
  const int lane = th & 63;
  const int w = th >> 6;         // wave 0..15
  const int g = lane >> 4;       // quad
  const int c = lane & 15;       // lane-in-quad
  const int fb = lane << 3;      // 8-feature chunk for LN

  // LDS 60,672 B
  __shared__ ushort_t h_bf[16*520];   // exclusive
  __shared__ ushort_t qk[9216];       // q[4][16][72] @0, k @4608; abuf_p(16x264) aliases q; dbuf(16x520) aliases qk
  __shared__ ushort_t vbuf[10240];    // vT[4][64][40]  EXCLUSIVE (pads zeroed once)
  __shared__ ushort_t p_lds[2560];    // P[4][16][40]   EXCLUSIVE (pad cols zeroed once)

  ushort_t* q_lds = qk;
  ushort_t* k_lds = qk + 4608;
  ushort_t* abuf_p = qk;
  ushort_t* dbuf = qk;

  const size_t hsb = (size_t)b * MEMD;
  const int ci0 = (int)hstate[hsb + 32768];

  float hreg[8];
#pragma unroll
  for (int j = 0; j < 8; ++j) {
    float v = hstate[hsb + (size_t)w*E + fb + j];
    hreg[j] = v;
    h_bf[w*520 + fb + j] = f2bf(v);
  }
  for (int i = th; i < 2560; i += 1024) p_lds[i] = 0;
  // zero vT token-pad cols 16..31 once (vbuf is exclusive now)
  for (int i = th; i < 4096; i += 1024) {
    int h2 = i >> 10, dh = (i >> 4) & 63, t16 = i & 15;
    vbuf[h2*2560 + dh*40 + 16 + t16] = 0;
  }
  bar_lds();

#pragma unroll 1
  for (int t = 0; t < SS; ++t) {
    const int cic = ci0 + t;
    // ---- stage A: h[cic] <- x_t ----
    if (cic < 16 && w == cic) {
#pragma unroll
      for (int j = 0; j < 8; ++j) {
        float v = Xpre[((size_t)t*BB + b)*E + fb + j];
        hreg[j] = v;
        h_bf[w*520 + fb + j] = f2bf(v);
      }
    }
    bar_lds();

#pragma unroll 1
    for (int l = 0; l < 2; ++l) {
      const ushort_t* wi = win_pk + (size_t)l*1536*E;
      const ushort_t* wo = wo_pk + (size_t)l*E*E;
      const ushort_t* wf = ff_pk + (size_t)l*E*E;
      const float* bqkv = ipb + l*1536;

      f32x4 oacc0 = {0.f,0.f,0.f,0.f}, oacc1 = oacc0;

#pragma unroll 1
      for (int pass = 0; pass < 2; ++pass) {
        const int hl = w >> 2;
        const int dhb = (w & 3) * 16;

        // ---- QKV: depth-4 prefetch, 12 loads in flight/wave ----
        {
          const ushort_t* A = h_bf + c*520 + g*8;
          const int Tq = pass*16 + w;
          const ushort_t* pq = wi + ((size_t)Tq*16)*512 + lane*8;
          const ushort_t* pk = pq + (size_t)32*16*512;
          const ushort_t* pv = pq + (size_t)64*16*512;
          f32x4 aq = {0.f,0.f,0.f,0.f}, ak = aq, av = aq;
          short8 bq[4], bk[4], bv[4];
#pragma unroll
          for (int i = 0; i < 4; ++i) {
            bq[i] = *(const short8*)(pq + i*512);
            bk[i] = *(const short8*)(pk + i*512);
            bv[i] = *(const short8*)(pv + i*512);
          }
#pragma unroll
          for (int kt = 0; kt < 16; ++kt) {
            short8 a = *(const short8*)(A + kt*32);
            aq = MFMA(a, bq[kt&3], aq, 0,0,0);
            ak = MFMA(a, bk[kt&3], ak, 0,0,0);
            av = MFMA(a, bv[kt&3], av, 0,0,0);
            if (kt < 12) {
              bq[kt&3] = *(const short8*)(pq + (kt+4)*512);
              bk[kt&3] = *(const short8*)(pk + (kt+4)*512);
              bv[kt&3] = *(const short8*)(pv + (kt+4)*512);
            }
          }
          const float biq = bqkv[pass*256 + w*16 + c];
          const float bik = bqkv[512 + pass*256 + w*16 + c];
          const float biv = bqkv[1024 + pass*256 + w*16 + c];
#pragma unroll
          for (int r = 0; r < 4; ++r) {
            int tok = 4*g + r;
            q_lds[hl*1152 + tok*72 + dhb + c] = f2bf(aq[r] + biq);
            k_lds[hl*1152 + tok*72 + dhb + c] = f2bf(ak[r] + bik);
            vbuf[hl*2560 + (dhb + c)*40 + tok] = f2bf(av[r] + biv);
          }
        }
        bar_lds();

        // ---- out-proj weight prefetch: stays in flight through softmax+PV ----
        short8 wob0[8], wob1[8];
        {
          const ushort_t* B0 = wo + ((size_t)w*16 + pass*8)*512 + lane*8;
          const ushort_t* B1 = wo + ((size_t)(w+16)*16 + pass*8)*512 + lane*8;
#pragma unroll
          for (int i = 0; i < 8; ++i) {
            wob0[i] = *(const short8*)(B0 + i*512);
            wob1[i] = *(const short8*)(B1 + i*512);
          }
        }

        // ---- scores + masked softmax: waves 0..3, one head each ----
        if (w < 4) {
          f32x4 sc = {0.f,0.f,0.f,0.f};
#pragma unroll
          for (int k2 = 0; k2 < 2; ++k2) {
            short8 qa = *(const short8*)&q_lds[w*1152 + c*72 + k2*32 + g*8];
            short8 kb = *(const short8*)&k_lds[w*1152 + c*72 + k2*32 + g*8];
            sc = MFMA(qa, kb, sc, 0,0,0);
          }
          float sv[4], mx[4], ex[4], sm[4];
#pragma unroll
          for (int r = 0; r < 4; ++r) {
            int row = 4*g + r;
            bool msk = ((c > cic) || (row > cic)) && (c != 0);
            sv[r] = msk ? NEGV : sc[r]*0.125f;
            mx[r] = sv[r];
          }
#pragma unroll
          for (int r = 0; r < 4; ++r) {
            mx[r] = fmaxf(mx[r], __shfl_xor(mx[r], 1));
            mx[r] = fmaxf(mx[r], __shfl_xor(mx[r], 2));
            mx[r] = fmaxf(mx[r], __shfl_xor(mx[r], 4));
            mx[r] = fmaxf(mx[r], __shfl_xor(mx[r], 8));
          }
#pragma unroll
          for (int r = 0; r < 4; ++r) { ex[r] = __expf(sv[r] - mx[r]); sm[r] = ex[r]; }
#pragma unroll
          for (int r = 0; r < 4; ++r) {
            sm[r] += __shfl_xor(sm[r], 1);
            sm[r] += __shfl_xor(sm[r], 2);
            sm[r] += __shfl_xor(sm[r], 4);
            sm[r] += __shfl_xor(sm[r], 8);
          }
#pragma unroll
          for (int r = 0; r < 4; ++r)
            p_lds[w*640 + (4*g + r)*40 + c] = f2bf(ex[r] / sm[r]);
        }
        bar_lds();

        // ---- PV: 16 tiles (4 heads x 4 col-tiles), one per wave ----
        {
          const int hl2 = w >> 2, ct = w & 3;
          short8 pa = *(const short8*)&p_lds[hl2*640 + c*40 + g*8];
          short8 vb = *(const short8*)&vbuf[hl2*2560 + (ct*16 + c)*40 + g*8];
          f32x4 ov = {0.f,0.f,0.f,0.f};
          ov = MFMA(pa, vb, ov, 0,0,0);
#pragma unroll
          for (int r = 0; r < 4; ++r)
            abuf_p[(4*g + r)*264 + hl2*64 + ct*16 + c] = f2bf(ov[r]);
        }
        bar_lds();

        // ---- out-proj partial MFMA (weights already in registers) ----
        {
          const ushort_t* A = abuf_p + c*264 + g*8;
#pragma unroll
          for (int kt = 0; kt < 8; ++kt) {
            short8 a = *(const short8*)(A + kt*32);
            oacc0 = MFMA(a, wob0[kt], oacc0, 0,0,0);
            oacc1 = MFMA(a, wob1[kt], oacc1, 0,0,0);
          }
        }
        bar_lds();
      } // pass

      // ---- write out-proj result ----
#pragma unroll
      for (int r = 0; r < 4; ++r) {
        dbuf[(4*g + r)*520 + w*16 + c]       = f2bf(oacc0[r]);
        dbuf[(4*g + r)*520 + 256 + w*16 + c] = f2bf(oacc1[r]);
      }
      bar_lds();

      // ---- FF weight prologue issued here, hides behind LN1 ----
      const ushort_t* Bf0 = wf + ((size_t)w*16)*512 + lane*8;
      const ushort_t* Bf1 = wf + ((size_t)(w+16)*16)*512 + lane*8;
      short8 fb0[4], fb1[4];
#pragma unroll
      for (int i = 0; i < 4; ++i) {
        fb0[i] = *(const short8*)(Bf0 + i*512);
        fb1[i] = *(const short8*)(Bf1 + i*512);
      }

      // ---- residual + LN1 ----
      {
        const float* bias = aob + l*E;
        const float* sc1 = l1s + l*E; const float* bi1 = l1b + l*E;
        float sum = 0.f;
#pragma unroll
        for (int j = 0; j < 8; ++j) {
          float d = bf2f(dbuf[w*520 + fb + j]) + bias[fb + j];
          hreg[j] += d; sum += hreg[j];
        }
        sum += __shfl_xor(sum, 1); sum += __shfl_xor(sum, 2); sum += __shfl_xor(sum, 4);
        sum += __shfl_xor(sum, 8); sum += __shfl_xor(sum, 16); sum += __shfl_xor(sum, 32);
        float mu = sum * (1.0f/512.0f);
        float s2 = 0.f;
#pragma unroll
        for (int j = 0; j < 8; ++j) { float dd = hreg[j] - mu; s2 += dd*dd; }
        s2 += __shfl_xor(s2, 1); s2 += __shfl_xor(s2, 2); s2 += __shfl_xor(s2, 4);
        s2 += __shfl_xor(s2, 8); s2 += __shfl_xor(s2, 16); s2 += __shfl_xor(s2, 32);
        float rs = rsqrtf(s2 * (1.0f/512.0f) + EPSV);
#pragma unroll
        for (int j = 0; j < 8; ++j) {
          float y = (hreg[j] - mu) * rs * sc1[fb + j] + bi1[fb + j];
          hreg[j] = y;
          h_bf[w*520 + fb + j] = f2bf(y);
        }
      }
      bar_lds();

      // ---- FF GEMM: 2 tiles/wave, depth-4 prefetch ----
      {
        f32x4 f0 = {0.f,0.f,0.f,0.f}, f1 = f0;
        const ushort_t* A = h_bf + c*520 + g*8;
#pragma unroll
        for (int kt = 0; kt < 16; ++kt) {
          short8 a = *(const short8*)(A + kt*32);
          f0 = MFMA(a, fb0[kt&3], f0, 0,0,0);
          f1 = MFMA(a, fb1[kt&3], f1, 0,0,0);
          if (kt < 12) {
            fb0[kt&3] = *(const short8*)(Bf0 + (kt+4)*512);
            fb1[kt&3] = *(const short8*)(Bf1 + (kt+4)*512);
          }
        }
        bar_lds();   // dbuf (aliases qk) free; also orders vs LN reads below
#pragma unroll
        for (int r = 0; r < 4; ++r) {
          dbuf[(4*g + r)*520 + w*16 + c]       = f2bf(f0[r]);
          dbuf[(4*g + r)*520 + 256 + w*16 + c] = f2bf(f1[r]);
        }
      }
      bar_lds();

      // ---- residual + LN2 ----
      {
        const float* bias = ffb + l*E;
        const float* sc2 = l2s + l*E; const float* bi2 = l2b + l*E;
        float sum = 0.f;
#pragma unroll
        for (int j = 0; j < 8; ++j) {
          float d = bf2f(dbuf[w*520 + fb + j]) + bias[fb + j];
          hreg[j] += d; sum += hreg[j];
        }
        sum += __shfl_xor(sum, 1); sum += __shfl_xor(sum, 2); sum += __shfl_xor(sum, 4);
        sum += __shfl_xor(sum, 8); sum += __shfl_xor(sum, 16); sum += __shfl_xor(sum, 32);
        float mu = sum * (1.0f/512.0f);
        float s2 = 0.f;
#pragma unroll
        for (int j = 0; j < 8; ++j) { float dd = hreg[j] - mu; s2 += dd*dd; }
        s2 += __shfl_xor(s2, 1); s2 += __shfl_xor(s2, 2); s2 += __shfl_xor(s2, 4);
        s2 += __shfl_xor(s2, 8); s2 += __shfl_xor(s2, 16); s2 += __shfl_xor(s2, 32);
        float rs = rsqrtf(s2 * (1.0f/512.0f) + EPSV);
#pragma unroll
        for (int j = 0; j < 8; ++j) {
          float y = (hreg[j] - mu) * rs * sc2[fb + j] + bi2[fb + j];
          hreg[j] = y;
          h_bf[w*520 + fb + j] = f2bf(y);
        }
      }
      bar_lds();
    } // layer

    // ---- output projection: out_t = h[cic] @ Wout^T + b_out (waves 0..7) ----
    if (w < 8) {
      const int crow = (cic < 15) ? cic : 15;
      const ushort_t* A = h_bf + c*520 + g*8;
      const ushort_t* B0 = wout_pk + ((size_t)w*16)*512 + lane*8;
      short8 wb[16];
#pragma unroll
      for (int i = 0; i < 16; ++i) wb[i] = *(const short8*)(B0 + i*512);
      f32x4 oo = {0.f,0.f,0.f,0.f};
#pragma unroll
      for (int kt = 0; kt < 16; ++kt)
        oo = MFMA(*(const short8*)(A + kt*32), wb[kt], oo, 0,0,0);
      if (g == (crow >> 2)) {
        int r = crow & 3;
        float val = (r == 0) ? oo[0] : (r == 1) ? oo[1] : (r == 2) ? oo[2] : oo[3];
        out[((size_t)t*BB + b)*OUTD + w*16 + c] = val + bout[w*16 + c];
      }
    }
    bar_lds();
  } // t

  // ---- epilogue: new_h = [h_fin, pad, ci+16] ----
  const size_t OB = (size_t)SS * BB * OUTD;
#pragma unroll
  for (int j = 0; j < 8; ++j)
    out[OB + hsb + (size_t)w*E + fb + j] = hreg[j];
  for (int i = th; i < 48*512; i += 1024)
    out[OB + hsb + 8192 + i] = hstate[hsb + 8192 + i];
  if (th == 0) out[OB + hsb + 32768] = (float)(ci0 + SS);
}

// ---------------- launcher ----------------
extern "C" void kernel_launch(void* const* d_in, const int* in_sizes, int n_in,
                              void* d_out, int out_size, void* d_ws, size_t ws_size,
                              hipStream_t stream) {
  const float* seq  = (const float*)d_in[0];
  const float* hs   = (const float*)d_in[1];
  const float* Win  = (const float*)d_in[2];
  const float* b_in = (const float*)d_in[3];
  const float* Wout = (const float*)d_in[4];
  const float* bo   = (const float*)d_in[5];
  const float* ipw  = (const float*)d_in[6];
  const float* ipb  = (const float*)d_in[7];
  const float* aow  = (const float*)d_in[8];
  const float* aob  = (const float*)d_in[9];
  const float* l1s  = (const float*)d_in[10];
  const float* l1b  = (const float*)d_in[11];
  const float* l2s  = (const float*)d_in[12];
  const float* l2b  = (const float*)d_in[13];
  const float* ffw  = (const float*)d_in[14];
  const float* ffb  = (const float*)d_in[15];

  char* ws = (char*)d_ws;
  ushort_t* win_pk  = (ushort_t*)(ws + 0);
  ushort_t* wo_pk   = (ushort_t*)(ws + 3145728);
  ushort_t* ff_pk   = (ushort_t*)(ws + 4194304);
  ushort_t* wout_pk = (ushort_t*)(ws + 5242880);
  float*    winT    = (float*)   (ws + 5373952);
  float*    X       = (float*)   (ws + 5898240);

  wconvert_kernel<<<512, 256, 0, stream>>>(ipw, aow, ffw, Wout, Win,
                                           win_pk, wo_pk, ff_pk, wout_pk, winT);
  xproj_kernel<<<BB, 512, 0, stream>>>(seq, winT, b_in, X);
  encoder_kernel<<<BB, 1024, 0, stream>>>(X, hs, win_pk, wo_pk, ff_pk, wout_pk,
                                          ipb, aob, l1s, l1b, l2s, l2b, ffb, bo,
                                          (float*)d_out);
}

// Round 4
// 1096.553 us; speedup vs baseline: 2.7453x; 1.0270x over previous
//
#include <hip/hip_runtime.h>

typedef __attribute__((ext_vector_type(8))) short short8;
typedef __attribute__((ext_vector_type(4))) float f32x4;
typedef unsigned short ushort_t;

#define E 512
#define NH 8
#define DH 64
#define SS 16
#define BB 128
#define IND 256
#define OUTD 128
#define MEMD 32769
#define NEGV -1000000000.0f
#define EPSV 1e-5f

#define MFMA __builtin_amdgcn_mfma_f32_16x16x32_bf16

// ---- forced-issue load machinery ------------------------------------------
// Load 16B to a VGPR quad via saddr-form global_load: base is wave-uniform
// (SGPR pair), voff is the per-lane byte offset. asm volatile => issue order
// among these loads/waits is preserved; compiler cannot sink them.
#define GL(dst, sbase, voff) \
  asm volatile("global_load_dwordx4 %0, %1, %2" \
               : "=v"(dst) : "v"(voff), "s"(sbase))

// s_waitcnt vmcnt(n) tied to the register we are about to consume: the tie
// makes every consumer of x data-depend on the wait.
#define WV(x, n) asm volatile("s_waitcnt vmcnt(" #n ")" : "+v"(x))

#define DRAIN6(a0,a1,a2,a3,a4,a5) \
  asm volatile("s_waitcnt vmcnt(0)" \
    : "+v"(a0),"+v"(a1),"+v"(a2),"+v"(a3),"+v"(a4),"+v"(a5))
#define DRAIN9(a0,a1,a2,a3,a4,a5,a6,a7,a8) \
  asm volatile("s_waitcnt vmcnt(0)" \
    : "+v"(a0),"+v"(a1),"+v"(a2),"+v"(a3),"+v"(a4),"+v"(a5),"+v"(a6),"+v"(a7),"+v"(a8))
#define WAIT8(n,a0,a1,a2,a3,a4,a5,a6,a7) \
  asm volatile("s_waitcnt vmcnt(" #n ")" \
    : "+v"(a0),"+v"(a1),"+v"(a2),"+v"(a3),"+v"(a4),"+v"(a5),"+v"(a6),"+v"(a7))

// LDS-visibility-only barrier (does NOT drain vmcnt): weight loads stay in
// flight across phases.
__device__ __forceinline__ void bar_lds() {
  asm volatile("s_waitcnt lgkmcnt(0)\ns_barrier" ::: "memory");
}

__device__ __forceinline__ unsigned short f2bf(float f) {
  union { float f; unsigned int u; } v; v.f = f;
  unsigned int u = v.u;
  unsigned int r = u + 0x7fffu + ((u >> 16) & 1u);
  return (unsigned short)(r >> 16);
}
__device__ __forceinline__ float bf2f(unsigned short h) {
  union { unsigned int u; float f; } v; v.u = ((unsigned int)h) << 16;
  return v.f;
}

// ---------------- K0: weight conversion into packed MFMA-tile layout ----------------
// dst[((T*16 + kt)*64 + lane)*8 + j] = W[T*16 + (lane&15)][kt*32 + (lane>>4)*8 + j]
__device__ __forceinline__ void packmat(ushort_t* __restrict__ dst, const float* __restrict__ src,
                                        int n, int tid, int stride) {
  for (int i = tid; i < n; i += stride) {
    int jj = i & 7, lane = (i >> 3) & 63, kt = (i >> 9) & 15, T = i >> 13;
    int row = T * 16 + (lane & 15);
    int col = kt * 32 + (lane >> 4) * 8 + jj;
    dst[i] = f2bf(src[row * 512 + col]);
  }
}

__global__ __launch_bounds__(256) void wconvert_kernel(
    const float* __restrict__ ipw, const float* __restrict__ aow,
    const float* __restrict__ ffw, const float* __restrict__ wout,
    const float* __restrict__ win,
    ushort_t* __restrict__ win_pk, ushort_t* __restrict__ wo_pk,
    ushort_t* __restrict__ ff_pk, ushort_t* __restrict__ wout_pk,
    float* __restrict__ winT)
{
  const int tid = blockIdx.x * blockDim.x + threadIdx.x;
  const int stride = gridDim.x * blockDim.x;
  packmat(win_pk, ipw, 2*1536*E, tid, stride);
  packmat(wo_pk,  aow, 2*E*E,    tid, stride);
  packmat(ff_pk,  ffw, 2*E*E,    tid, stride);
  packmat(wout_pk, wout, OUTD*E, tid, stride);
  for (int i = tid; i < E*IND; i += stride) {
    int o = i / IND, k = i % IND;
    winT[k*E + o] = win[i];
  }
}

// ---------------- K1: X = seq @ Win^T + b_in ----------------
__global__ __launch_bounds__(512) void xproj_kernel(
    const float* __restrict__ seq, const float* __restrict__ winT,
    const float* __restrict__ b_in, float* __restrict__ X)
{
  const int b = blockIdx.x;
  const int th = threadIdx.x;
  __shared__ float sq[SS * IND];
  for (int i = th; i < SS * IND; i += 512) {
    int t = i >> 8, k = i & 255;
    sq[i] = seq[((size_t)t * BB + b) * IND + k];
  }
  __syncthreads();
  float acc[SS];
#pragma unroll
  for (int t = 0; t < SS; ++t) acc[t] = 0.f;
  for (int k = 0; k < IND; ++k) {
    float w = winT[k * E + th];
#pragma unroll
    for (int t = 0; t < SS; ++t) acc[t] += sq[t * IND + k] * w;
  }
  float bias = b_in[th];
#pragma unroll
  for (int t = 0; t < SS; ++t)
    X[((size_t)t * BB + b) * E + th] = acc[t] + bias;
}

// ---------------- K2: main recurrent encoder, one block (1024 thr) per batch elem ----------------
__global__ __launch_bounds__(1024, 4) void encoder_kernel(
    const float* __restrict__ Xpre, const float* __restrict__ hstate,
    const ushort_t* __restrict__ win_pk, const ushort_t* __restrict__ wo_pk,
    const ushort_t* __restrict__ ff_pk, const ushort_t* __restrict__ wout_pk,
    const float* __restrict__ ipb, const float* __restrict__ aob,
    const float* __restrict__ l1s, const float* __restrict__ l1b,
    const float* __restrict__ l2s, const float* __restrict__ l2b,
    const float* __restrict__ ffb, const float* __restrict__ bout,
    float* __restrict__ out)
{
  const int b = blockIdx.x;
  const int th = threadIdx.x;
  const int lane = th & 63;
  const int w = th >> 6;         // wave 0..15
  const int g = lane >> 4;       // quad
  const int c = lane & 15;       // lane-in-quad
  const int fb = lane << 3;      // 8-feature chunk for LN

  // shared per-lane byte offset used by every packed-weight load:
  // tile row-block (w*16 rows => w*16*512 elem => w*16384 B) + lane*16 B
  const unsigned int vgo = (unsigned int)w * 16384u + (unsigned int)lane * 16u;

  // LDS 60,672 B
  __shared__ ushort_t h_bf[16*520];
  __shared__ ushort_t qk[9216];       // q[4][16][72] @0, k @4608; abuf_p/dbuf alias
  __shared__ ushort_t vbuf[10240];    // vT[4][64][40] exclusive (pads zeroed once)
  __shared__ ushort_t p_lds[2560];    // P[4][16][40]  exclusive (pad cols zeroed once)

  ushort_t* q_lds = qk;
  ushort_t* k_lds = qk + 4608;
  ushort_t* abuf_p = qk;
  ushort_t* dbuf = qk;

  const size_t hsb = (size_t)b * MEMD;
  const int ci0 = (int)hstate[hsb + 32768];

  float hreg[8];
#pragma unroll
  for (int j = 0; j < 8; ++j) {
    float v = hstate[hsb + (size_t)w*E + fb + j];
    hreg[j] = v;
    h_bf[w*520 + fb + j] = f2bf(v);
  }
  for (int i = th; i < 2560; i += 1024) p_lds[i] = 0;
  for (int i = th; i < 4096; i += 1024) {
    int h2 = i >> 10, dh = (i >> 4) & 63, t16 = i & 15;
    vbuf[h2*2560 + dh*40 + 16 + t16] = 0;
  }
  bar_lds();

#pragma unroll 1
  for (int t = 0; t < SS; ++t) {
    const int cic = ci0 + t;
    if (cic < 16 && w == cic) {
#pragma unroll
      for (int j = 0; j < 8; ++j) {
        float v = Xpre[((size_t)t*BB + b)*E + fb + j];
        hreg[j] = v;
        h_bf[w*520 + fb + j] = f2bf(v);
      }
    }
    bar_lds();

#pragma unroll 1
    for (int l = 0; l < 2; ++l) {
      const ushort_t* wi = win_pk + (size_t)l*1536*E;
      const ushort_t* wo = wo_pk + (size_t)l*E*E;
      const ushort_t* wf = ff_pk + (size_t)l*E*E;
      const float* bqkv = ipb + l*1536;

      f32x4 oacc0 = {0.f,0.f,0.f,0.f}, oacc1 = oacc0;

#pragma unroll 1
      for (int pass = 0; pass < 2; ++pass) {
        const int hl = w >> 2;
        const int dhb = (w & 3) * 16;

        // ---- QKV: forced depth-4 x 3-stream pipeline (12 loads in flight) ----
        {
          const ushort_t* A = h_bf + c*520 + g*8;
          // uniform bases (pass offset folded into saddr)
          const ushort_t* uq = wi + (size_t)pass*131072;
          const ushort_t* uk = uq + 262144;
          const ushort_t* uv = uq + 524288;
          f32x4 aq = {0.f,0.f,0.f,0.f}, ak = aq, av = aq;
          short8 bq[4], bk[4], bv[4];
          GL(bq[0], uq,        vgo); GL(bk[0], uk,        vgo); GL(bv[0], uv,        vgo);
          GL(bq[1], uq +  512, vgo); GL(bk[1], uk +  512, vgo); GL(bv[1], uv +  512, vgo);
          GL(bq[2], uq + 1024, vgo); GL(bk[2], uk + 1024, vgo); GL(bv[2], uv + 1024, vgo);
          GL(bq[3], uq + 1536, vgo); GL(bk[3], uk + 1536, vgo); GL(bv[3], uv + 1536, vgo);

#define QKV_STEP(kt) { \
            short8 a = *(const short8*)(A + (kt)*32); \
            WV(bq[(kt)&3], 11); aq = MFMA(a, bq[(kt)&3], aq, 0,0,0); \
            WV(bk[(kt)&3], 10); ak = MFMA(a, bk[(kt)&3], ak, 0,0,0); \
            WV(bv[(kt)&3],  9); av = MFMA(a, bv[(kt)&3], av, 0,0,0); \
            if ((kt) < 12) { \
              GL(bq[(kt)&3], uq + ((kt)+4)*512, vgo); \
              GL(bk[(kt)&3], uk + ((kt)+4)*512, vgo); \
              GL(bv[(kt)&3], uv + ((kt)+4)*512, vgo); \
            } }
          QKV_STEP(0)  QKV_STEP(1)  QKV_STEP(2)  QKV_STEP(3)
          QKV_STEP(4)  QKV_STEP(5)  QKV_STEP(6)  QKV_STEP(7)
          QKV_STEP(8)  QKV_STEP(9)  QKV_STEP(10) QKV_STEP(11)
          QKV_STEP(12)
          DRAIN9(bq[1],bk[1],bv[1], bq[2],bk[2],bv[2], bq[3],bk[3],bv[3]);
          {
            short8 a = *(const short8*)(A + 13*32);
            aq = MFMA(a, bq[1], aq, 0,0,0);
            ak = MFMA(a, bk[1], ak, 0,0,0);
            av = MFMA(a, bv[1], av, 0,0,0);
            a = *(const short8*)(A + 14*32);
            aq = MFMA(a, bq[2], aq, 0,0,0);
            ak = MFMA(a, bk[2], ak, 0,0,0);
            av = MFMA(a, bv[2], av, 0,0,0);
            a = *(const short8*)(A + 15*32);
            aq = MFMA(a, bq[3], aq, 0,0,0);
            ak = MFMA(a, bk[3], ak, 0,0,0);
            av = MFMA(a, bv[3], av, 0,0,0);
          }
          const float biq = bqkv[pass*256 + w*16 + c];
          const float bik = bqkv[512 + pass*256 + w*16 + c];
          const float biv = bqkv[1024 + pass*256 + w*16 + c];
#pragma unroll
          for (int r = 0; r < 4; ++r) {
            int tok = 4*g + r;
            q_lds[hl*1152 + tok*72 + dhb + c] = f2bf(aq[r] + biq);
            k_lds[hl*1152 + tok*72 + dhb + c] = f2bf(ak[r] + bik);
            vbuf[hl*2560 + (dhb + c)*40 + tok] = f2bf(av[r] + biv);
          }
        }
        bar_lds();

        // ---- out-proj weights: 16 forced loads, in flight through softmax+PV ----
        short8 wob0[8], wob1[8];
        {
          const ushort_t* u0 = wo + pass*4096;
          const ushort_t* u1 = u0 + 131072;
          GL(wob0[0], u0,        vgo); GL(wob1[0], u1,        vgo);
          GL(wob0[1], u0 +  512, vgo); GL(wob1[1], u1 +  512, vgo);
          GL(wob0[2], u0 + 1024, vgo); GL(wob1[2], u1 + 1024, vgo);
          GL(wob0[3], u0 + 1536, vgo); GL(wob1[3], u1 + 1536, vgo);
          GL(wob0[4], u0 + 2048, vgo); GL(wob1[4], u1 + 2048, vgo);
          GL(wob0[5], u0 + 2560, vgo); GL(wob1[5], u1 + 2560, vgo);
          GL(wob0[6], u0 + 3072, vgo); GL(wob1[6], u1 + 3072, vgo);
          GL(wob0[7], u0 + 3584, vgo); GL(wob1[7], u1 + 3584, vgo);
        }

        // ---- scores + masked softmax: waves 0..3, one head each ----
        if (w < 4) {
          f32x4 sc = {0.f,0.f,0.f,0.f};
#pragma unroll
          for (int k2 = 0; k2 < 2; ++k2) {
            short8 qa = *(const short8*)&q_lds[w*1152 + c*72 + k2*32 + g*8];
            short8 kb = *(const short8*)&k_lds[w*1152 + c*72 + k2*32 + g*8];
            sc = MFMA(qa, kb, sc, 0,0,0);
          }
          float sv[4], mx[4], ex[4], sm[4];
#pragma unroll
          for (int r = 0; r < 4; ++r) {
            int row = 4*g + r;
            bool msk = ((c > cic) || (row > cic)) && (c != 0);
            sv[r] = msk ? NEGV : sc[r]*0.125f;
            mx[r] = sv[r];
          }
#pragma unroll
          for (int r = 0; r < 4; ++r) {
            mx[r] = fmaxf(mx[r], __shfl_xor(mx[r], 1));
            mx[r] = fmaxf(mx[r], __shfl_xor(mx[r], 2));
            mx[r] = fmaxf(mx[r], __shfl_xor(mx[r], 4));
            mx[r] = fmaxf(mx[r], __shfl_xor(mx[r], 8));
          }
#pragma unroll
          for (int r = 0; r < 4; ++r) { ex[r] = __expf(sv[r] - mx[r]); sm[r] = ex[r]; }
#pragma unroll
          for (int r = 0; r < 4; ++r) {
            sm[r] += __shfl_xor(sm[r], 1);
            sm[r] += __shfl_xor(sm[r], 2);
            sm[r] += __shfl_xor(sm[r], 4);
            sm[r] += __shfl_xor(sm[r], 8);
          }
#pragma unroll
          for (int r = 0; r < 4; ++r)
            p_lds[w*640 + (4*g + r)*40 + c] = f2bf(ex[r] / sm[r]);
        }
        bar_lds();

        // ---- PV ----
        {
          const int hl2 = w >> 2, ct = w & 3;
          short8 pa = *(const short8*)&p_lds[hl2*640 + c*40 + g*8];
          short8 vb = *(const short8*)&vbuf[hl2*2560 + (ct*16 + c)*40 + g*8];
          f32x4 ov = {0.f,0.f,0.f,0.f};
          ov = MFMA(pa, vb, ov, 0,0,0);
#pragma unroll
          for (int r = 0; r < 4; ++r)
            abuf_p[(4*g + r)*264 + hl2*64 + ct*16 + c] = f2bf(ov[r]);
        }
        bar_lds();

        // ---- out-proj partial MFMA (K=256), two-half drain ----
        {
          const ushort_t* A = abuf_p + c*264 + g*8;
          WAIT8(8, wob0[0],wob1[0],wob0[1],wob1[1],wob0[2],wob1[2],wob0[3],wob1[3]);
#pragma unroll
          for (int kt = 0; kt < 4; ++kt) {
            short8 a = *(const short8*)(A + kt*32);
            oacc0 = MFMA(a, wob0[kt], oacc0, 0,0,0);
            oacc1 = MFMA(a, wob1[kt], oacc1, 0,0,0);
          }
          WAIT8(0, wob0[4],wob1[4],wob0[5],wob1[5],wob0[6],wob1[6],wob0[7],wob1[7]);
#pragma unroll
          for (int kt = 4; kt < 8; ++kt) {
            short8 a = *(const short8*)(A + kt*32);
            oacc0 = MFMA(a, wob0[kt], oacc0, 0,0,0);
            oacc1 = MFMA(a, wob1[kt], oacc1, 0,0,0);
          }
        }
        bar_lds();
      } // pass

      // ---- write out-proj result ----
#pragma unroll
      for (int r = 0; r < 4; ++r) {
        dbuf[(4*g + r)*520 + w*16 + c]       = f2bf(oacc0[r]);
        dbuf[(4*g + r)*520 + 256 + w*16 + c] = f2bf(oacc1[r]);
      }
      bar_lds();

      // ---- FF weight prologue (8 forced loads), hides behind LN1 ----
      short8 fb0[4], fb1[4];
      {
        const ushort_t* u0 = wf;
        const ushort_t* u1 = wf + 131072;
        GL(fb0[0], u0,        vgo); GL(fb1[0], u1,        vgo);
        GL(fb0[1], u0 +  512, vgo); GL(fb1[1], u1 +  512, vgo);
        GL(fb0[2], u0 + 1024, vgo); GL(fb1[2], u1 + 1024, vgo);
        GL(fb0[3], u0 + 1536, vgo); GL(fb1[3], u1 + 1536, vgo);
      }

      // ---- residual + LN1 ----
      {
        const float* bias = aob + l*E;
        const float* sc1 = l1s + l*E; const float* bi1 = l1b + l*E;
        float sum = 0.f;
#pragma unroll
        for (int j = 0; j < 8; ++j) {
          float d = bf2f(dbuf[w*520 + fb + j]) + bias[fb + j];
          hreg[j] += d; sum += hreg[j];
        }
        sum += __shfl_xor(sum, 1); sum += __shfl_xor(sum, 2); sum += __shfl_xor(sum, 4);
        sum += __shfl_xor(sum, 8); sum += __shfl_xor(sum, 16); sum += __shfl_xor(sum, 32);
        float mu = sum * (1.0f/512.0f);
        float s2 = 0.f;
#pragma unroll
        for (int j = 0; j < 8; ++j) { float dd = hreg[j] - mu; s2 += dd*dd; }
        s2 += __shfl_xor(s2, 1); s2 += __shfl_xor(s2, 2); s2 += __shfl_xor(s2, 4);
        s2 += __shfl_xor(s2, 8); s2 += __shfl_xor(s2, 16); s2 += __shfl_xor(s2, 32);
        float rs = rsqrtf(s2 * (1.0f/512.0f) + EPSV);
#pragma unroll
        for (int j = 0; j < 8; ++j) {
          float y = (hreg[j] - mu) * rs * sc1[fb + j] + bi1[fb + j];
          hreg[j] = y;
          h_bf[w*520 + fb + j] = f2bf(y);
        }
      }
      bar_lds();

      // ---- FF GEMM: forced depth-4 x 2-stream pipeline ----
      {
        f32x4 f0 = {0.f,0.f,0.f,0.f}, f1 = f0;
        const ushort_t* A = h_bf + c*520 + g*8;
        const ushort_t* u0 = wf;
        const ushort_t* u1 = wf + 131072;
#define FF_STEP(kt) { \
          short8 a = *(const short8*)(A + (kt)*32); \
          WV(fb0[(kt)&3], 7); f0 = MFMA(a, fb0[(kt)&3], f0, 0,0,0); \
          WV(fb1[(kt)&3], 6); f1 = MFMA(a, fb1[(kt)&3], f1, 0,0,0); \
          if ((kt) < 12) { \
            GL(fb0[(kt)&3], u0 + ((kt)+4)*512, vgo); \
            GL(fb1[(kt)&3], u1 + ((kt)+4)*512, vgo); \
          } }
        FF_STEP(0)  FF_STEP(1)  FF_STEP(2)  FF_STEP(3)
        FF_STEP(4)  FF_STEP(5)  FF_STEP(6)  FF_STEP(7)
        FF_STEP(8)  FF_STEP(9)  FF_STEP(10) FF_STEP(11)
        FF_STEP(12)
        DRAIN6(fb0[1],fb1[1],fb0[2],fb1[2],fb0[3],fb1[3]);
        {
          short8 a = *(const short8*)(A + 13*32);
          f0 = MFMA(a, fb0[1], f0, 0,0,0);
          f1 = MFMA(a, fb1[1], f1, 0,0,0);
          a = *(const short8*)(A + 14*32);
          f0 = MFMA(a, fb0[2], f0, 0,0,0);
          f1 = MFMA(a, fb1[2], f1, 0,0,0);
          a = *(const short8*)(A + 15*32);
          f0 = MFMA(a, fb0[3], f0, 0,0,0);
          f1 = MFMA(a, fb1[3], f1, 0,0,0);
        }
        bar_lds();   // dbuf (aliases qk) free
#pragma unroll
        for (int r = 0; r < 4; ++r) {
          dbuf[(4*g + r)*520 + w*16 + c]       = f2bf(f0[r]);
          dbuf[(4*g + r)*520 + 256 + w*16 + c] = f2bf(f1[r]);
        }
      }
      bar_lds();

      // ---- residual + LN2 ----
      {
        const float* bias = ffb + l*E;
        const float* sc2 = l2s + l*E; const float* bi2 = l2b + l*E;
        float sum = 0.f;
#pragma unroll
        for (int j = 0; j < 8; ++j) {
          float d = bf2f(dbuf[w*520 + fb + j]) + bias[fb + j];
          hreg[j] += d; sum += hreg[j];
        }
        sum += __shfl_xor(sum, 1); sum += __shfl_xor(sum, 2); sum += __shfl_xor(sum, 4);
        sum += __shfl_xor(sum, 8); sum += __shfl_xor(sum, 16); sum += __shfl_xor(sum, 32);
        float mu = sum * (1.0f/512.0f);
        float s2 = 0.f;
#pragma unroll
        for (int j = 0; j < 8; ++j) { float dd = hreg[j] - mu; s2 += dd*dd; }
        s2 += __shfl_xor(s2, 1); s2 += __shfl_xor(s2, 2); s2 += __shfl_xor(s2, 4);
        s2 += __shfl_xor(s2, 8); s2 += __shfl_xor(s2, 16); s2 += __shfl_xor(s2, 32);
        float rs = rsqrtf(s2 * (1.0f/512.0f) + EPSV);
#pragma unroll
        for (int j = 0; j < 8; ++j) {
          float y = (hreg[j] - mu) * rs * sc2[fb + j] + bi2[fb + j];
          hreg[j] = y;
          h_bf[w*520 + fb + j] = f2bf(y);
        }
      }
      bar_lds();
    } // layer

    // ---- output projection: out_t = h[cic] @ Wout^T + b_out (waves 0..7) ----
    if (w < 8) {
      const int crow = (cic < 15) ? cic : 15;
      const ushort_t* A = h_bf + c*520 + g*8;
      short8 wb[16];
      GL(wb[0],  wout_pk,         vgo); GL(wb[1],  wout_pk +  512, vgo);
      GL(wb[2],  wout_pk + 1024,  vgo); GL(wb[3],  wout_pk + 1536, vgo);
      GL(wb[4],  wout_pk + 2048,  vgo); GL(wb[5],  wout_pk + 2560, vgo);
      GL(wb[6],  wout_pk + 3072,  vgo); GL(wb[7],  wout_pk + 3584, vgo);
      GL(wb[8],  wout_pk + 4096,  vgo); GL(wb[9],  wout_pk + 4608, vgo);
      GL(wb[10], wout_pk + 5120,  vgo); GL(wb[11], wout_pk + 5632, vgo);
      GL(wb[12], wout_pk + 6144,  vgo); GL(wb[13], wout_pk + 6656, vgo);
      GL(wb[14], wout_pk + 7168,  vgo); GL(wb[15], wout_pk + 7680, vgo);
      f32x4 oo = {0.f,0.f,0.f,0.f};
      WAIT8(8, wb[0],wb[1],wb[2],wb[3],wb[4],wb[5],wb[6],wb[7]);
#pragma unroll
      for (int kt = 0; kt < 8; ++kt)
        oo = MFMA(*(const short8*)(A + kt*32), wb[kt], oo, 0,0,0);
      WAIT8(0, wb[8],wb[9],wb[10],wb[11],wb[12],wb[13],wb[14],wb[15]);
#pragma unroll
      for (int kt = 8; kt < 16; ++kt)
        oo = MFMA(*(const short8*)(A + kt*32), wb[kt], oo, 0,0,0);
      if (g == (crow >> 2)) {
        int r = crow & 3;
        float val = (r == 0) ? oo[0] : (r == 1) ? oo[1] : (r == 2) ? oo[2] : oo[3];
        out[((size_t)t*BB + b)*OUTD + w*16 + c] = val + bout[w*16 + c];
      }
    }
    bar_lds();
  } // t

  // ---- epilogue: new_h = [h_fin, pad, ci+16] ----
  const size_t OB = (size_t)SS * BB * OUTD;
#pragma unroll
  for (int j = 0; j < 8; ++j)
    out[OB + hsb + (size_t)w*E + fb + j] = hreg[j];
  for (int i = th; i < 48*512; i += 1024)
    out[OB + hsb + 8192 + i] = hstate[hsb + 8192 + i];
  if (th == 0) out[OB + hsb + 32768] = (float)(ci0 + SS);
}

// ---------------- launcher ----------------
extern "C" void kernel_launch(void* const* d_in, const int* in_sizes, int n_in,
                              void* d_out, int out_size, void* d_ws, size_t ws_size,
                              hipStream_t stream) {
  const float* seq  = (const float*)d_in[0];
  const float* hs   = (const float*)d_in[1];
  const float* Win  = (const float*)d_in[2];
  const float* b_in = (const float*)d_in[3];
  const float* Wout = (const float*)d_in[4];
  const float* bo   = (const float*)d_in[5];
  const float* ipw  = (const float*)d_in[6];
  const float* ipb  = (const float*)d_in[7];
  const float* aow  = (const float*)d_in[8];
  const float* aob  = (const float*)d_in[9];
  const float* l1s  = (const float*)d_in[10];
  const float* l1b  = (const float*)d_in[11];
  const float* l2s  = (const float*)d_in[12];
  const float* l2b  = (const float*)d_in[13];
  const float* ffw  = (const float*)d_in[14];
  const float* ffb  = (const float*)d_in[15];

  char* ws = (char*)d_ws;
  ushort_t* win_pk  = (ushort_t*)(ws + 0);
  ushort_t* wo_pk   = (ushort_t*)(ws + 3145728);
  ushort_t* ff_pk   = (ushort_t*)(ws + 4194304);
  ushort_t* wout_pk = (ushort_t*)(ws + 5242880);
  float*    winT    = (float*)   (ws + 5373952);
  float*    X       = (float*)   (ws + 5898240);

  wconvert_kernel<<<512, 256, 0, stream>>>(ipw, aow, ffw, Wout, Win,
                                           win_pk, wo_pk, ff_pk, wout_pk, winT);
  xproj_kernel<<<BB, 512, 0, stream>>>(seq, winT, b_in, X);
  encoder_kernel<<<BB, 1024, 0, stream>>>(X, hs, win_pk, wo_pk, ff_pk, wout_pk,
                                          ipb, aob, l1s, l1b, l2s, l2b, ffb, bo,
                                          (float*)d_out);
}

// Round 7
// 825.292 us; speedup vs baseline: 3.6476x; 1.3287x over previous
//
#include <hip/hip_runtime.h>

typedef __attribute__((ext_vector_type(8))) short short8;
typedef __attribute__((ext_vector_type(4))) float f32x4;
typedef __attribute__((ext_vector_type(4))) int int4v;
typedef unsigned short ushort_t;
typedef unsigned char u8;

#define E 512
#define SS 16
#define BB 128
#define IND 256
#define OUTD 128
#define MEMD 32769
#define NEGV -1000000000.0f
#define EPSV 1e-5f

#define MFMA  __builtin_amdgcn_mfma_f32_16x16x32_bf16
#define MFMAI8(a, b, c) __builtin_amdgcn_mfma_i32_16x16x64_i8((a), (b), (c), 0, 0, 0)

// forced-issue 16B load, saddr form: base block-uniform (SGPR pair),
// thread-dependent terms in the per-lane VGPR offset.
#define GLV(dst, base, off) \
  asm volatile("global_load_dwordx4 %0, %1, %2" : "=v"(dst) : "v"(off), "s"(base))
// wait tied to consumed register
#define WVX_(x, n) asm volatile("s_waitcnt vmcnt(" #n ")" : "+v"(x))
#define WVX(x, n) WVX_(x, n)

// LDS-only barrier: does not drain vmcnt
__device__ __forceinline__ void bar_lds() {
  asm volatile("s_waitcnt lgkmcnt(0)\ns_barrier" ::: "memory");
}

__device__ __forceinline__ unsigned short f2bf(float f) {
  union { float f; unsigned int u; } v; v.f = f;
  unsigned int u = v.u;
  unsigned int r = u + 0x7fffu + ((u >> 16) & 1u);
  return (unsigned short)(r >> 16);
}
__device__ __forceinline__ float bf2f(unsigned short h) {
  union { unsigned int u; float f; } v; v.u = ((unsigned int)h) << 16;
  return v.f;
}
__device__ __forceinline__ int q8(float x) {  // round-to-nearest int8 with clamp
  return __float2int_rn(fminf(fmaxf(x, -127.f), 127.f));
}
// quantize 8 fp32 (scale 32) -> 8 int8 packed into two dwords at dst
__device__ __forceinline__ void quant8_store(u8* dst, const float* h) {
  int q[8];
#pragma unroll
  for (int j = 0; j < 8; ++j) q[j] = q8(h[j] * 32.f);
  unsigned int p0 = (q[0]&255) | ((q[1]&255)<<8) | ((q[2]&255)<<16) | ((q[3]&255)<<24);
  unsigned int p1 = (q[4]&255) | ((q[5]&255)<<8) | ((q[6]&255)<<16) | ((q[7]&255)<<24);
  *(unsigned int*)(dst)     = p0;
  *(unsigned int*)(dst + 4) = p1;
}

// ---------------- K0a: per-row weight scales ----------------
// scl rows: [0,3072)=ipw(2x1536), [3072,4096)=aow(2x512), [4096,5120)=ffw(2x512), [5120,5248)=wout(128)
__global__ __launch_bounds__(256) void wscale_kernel(
    const float* __restrict__ ipw, const float* __restrict__ aow,
    const float* __restrict__ ffw, const float* __restrict__ wout,
    float* __restrict__ scl)
{
  int tid = blockIdx.x * blockDim.x + threadIdx.x;
  if (tid >= 5248) return;
  const float* row;
  if (tid < 3072)      row = ipw  + (size_t)tid * 512;
  else if (tid < 4096) row = aow  + (size_t)(tid - 3072) * 512;
  else if (tid < 5120) row = ffw  + (size_t)(tid - 4096) * 512;
  else                 row = wout + (size_t)(tid - 5120) * 512;
  float m = 0.f;
  for (int k = 0; k < 512; ++k) m = fmaxf(m, fabsf(row[k]));
  scl[tid] = (m > 0.f) ? m * (1.f / 127.f) : 1.f;
}

// ---------------- K0b: pack weights to int8 MFMA tiles ----------------
// dst[((T*8+kt)*64+lane)*16 + j] = i8(W[T*16+(lane&15)][kt*64+(lane>>4)*16+j] / scl_row)
__device__ __forceinline__ void packmatI8(u8* __restrict__ dst, const float* __restrict__ src,
                                          const float* __restrict__ sclrow,
                                          int n, int tid, int stride) {
  for (int i = tid; i < n; i += stride) {
    int j = i & 15, lane = (i >> 4) & 63, kt = (i >> 10) & 7, T = i >> 13;
    int row = T * 16 + (lane & 15);
    int col = kt * 64 + ((lane >> 4) << 4) + j;
    float s = sclrow[row];
    int q = q8(src[(size_t)row * 512 + col] / s);
    dst[i] = (u8)(q & 0xff);
  }
}

__global__ __launch_bounds__(256) void wconvert_kernel(
    const float* __restrict__ ipw, const float* __restrict__ aow,
    const float* __restrict__ ffw, const float* __restrict__ wout,
    const float* __restrict__ win, const float* __restrict__ scl,
    u8* __restrict__ win8, u8* __restrict__ wo8,
    u8* __restrict__ wf8, u8* __restrict__ wout8,
    float* __restrict__ winT)
{
  const int tid = blockIdx.x * blockDim.x + threadIdx.x;
  const int stride = gridDim.x * blockDim.x;
  packmatI8(win8,  ipw,  scl,        2*1536*E, tid, stride);
  packmatI8(wo8,   aow,  scl + 3072, 2*E*E,    tid, stride);
  packmatI8(wf8,   ffw,  scl + 4096, 2*E*E,    tid, stride);
  packmatI8(wout8, wout, scl + 5120, OUTD*E,   tid, stride);
  for (int i = tid; i < E*IND; i += stride) {
    int o = i / IND, k = i % IND;
    winT[k*E + o] = win[i];
  }
}

// ---------------- K1: X = seq @ Win^T + b_in ----------------
__global__ __launch_bounds__(512) void xproj_kernel(
    const float* __restrict__ seq, const float* __restrict__ winT,
    const float* __restrict__ b_in, float* __restrict__ X)
{
  const int b = blockIdx.x;
  const int th = threadIdx.x;
  __shared__ float sq[SS * IND];
  for (int i = th; i < SS * IND; i += 512) {
    int t = i >> 8, k = i & 255;
    sq[i] = seq[((size_t)t * BB + b) * IND + k];
  }
  __syncthreads();
  float acc[SS];
#pragma unroll
  for (int t = 0; t < SS; ++t) acc[t] = 0.f;
  for (int k = 0; k < IND; ++k) {
    float w = winT[k * E + th];
#pragma unroll
    for (int t = 0; t < SS; ++t) acc[t] += sq[t * IND + k] * w;
  }
  float bias = b_in[th];
#pragma unroll
  for (int t = 0; t < SS; ++t)
    X[((size_t)t * BB + b) * E + th] = acc[t] + bias;
}

// ---------------- K2: main recurrent encoder ----------------
__global__ __launch_bounds__(1024, 4) void encoder_kernel(
    const float* __restrict__ Xpre, const float* __restrict__ hstate,
    const u8* __restrict__ win8, const u8* __restrict__ wo8,
    const u8* __restrict__ wf8, const u8* __restrict__ wout8,
    const float* __restrict__ scl,
    const float* __restrict__ ipb, const float* __restrict__ aob,
    const float* __restrict__ l1s, const float* __restrict__ l1b,
    const float* __restrict__ l2s, const float* __restrict__ l2b,
    const float* __restrict__ ffb, const float* __restrict__ bout,
    float* __restrict__ out)
{
  const int b = blockIdx.x;
  const int th = threadIdx.x;
  const int lane = th & 63;
  const int w = th >> 6;         // wave 0..15
  const int g = lane >> 4;       // quad
  const int c = lane & 15;       // lane-in-quad
  const int fb = lane << 3;      // 8-feature chunk for LN
  const int fq = w*16 + c;       // per-lane output-feature index within a 256-block

  // per-lane byte offsets for packed-weight loads (tile w + lane + chunk)
  unsigned int vofs[8];
#pragma unroll
  for (int i = 0; i < 8; ++i)
    vofs[i] = (unsigned int)w * 8192u + (unsigned int)lane * 16u + (unsigned int)i * 1024u;

  // LDS ~61 KB
  __shared__ u8 h_i8[16*528];         // h int8 (x32), stride 528 (16B aligned)
  __shared__ ushort_t qk[9216];       // q[4][16][72], k[4][16][72]; dbuf/abuf alias
  __shared__ ushort_t vbuf[10240];    // vT[4][64][40] bf16 (token pads zeroed once)
  __shared__ ushort_t p_lds[2560];    // P[4][16][40] bf16 (pad cols zeroed once)
  __shared__ ushort_t lnp[4096];      // [l][{l1s,l1b,l2s,l2b}][512] bf16

  ushort_t* q_lds = qk;
  ushort_t* k_lds = qk + 4608;
  u8* abuf_i8 = (u8*)qk;              // [16][272] int8 (x32)
  ushort_t* dbuf = qk;                // [16][520] bf16

  const size_t hsb = (size_t)b * MEMD;
  const int ci0 = (int)hstate[hsb + 32768];
  const float boutr = bout[(w&7)*16 + c];
  const float mw = scl[5120 + (w&7)*16 + c] * (1.f/32.f);

  float hreg[8];
  {
#pragma unroll
    for (int j = 0; j < 8; ++j) hreg[j] = hstate[hsb + (size_t)w*E + fb + j];
    quant8_store(h_i8 + w*528 + fb, hreg);
  }
  for (int i = th; i < 2560; i += 1024) p_lds[i] = 0;
  for (int i = th; i < 4096; i += 1024) {
    int h2 = i >> 10, dh = (i >> 4) & 63, t16 = i & 15;
    vbuf[h2*2560 + dh*40 + 16 + t16] = 0;
  }
  for (int i = th; i < 4096; i += 1024) {
    int l = i >> 11, arr = (i >> 9) & 3, idx = i & 511;
    float v = (arr == 0 ? l1s : arr == 1 ? l1b : arr == 2 ? l2s : l2b)[l*512 + idx];
    lnp[i] = f2bf(v);
  }
  bar_lds();

#pragma unroll 1
  for (int t = 0; t < SS; ++t) {
    const int cic = ci0 + t;
    if (cic < 16 && w == cic) {
#pragma unroll
      for (int j = 0; j < 8; ++j) hreg[j] = Xpre[((size_t)t*BB + b)*E + fb + j];
      quant8_store(h_i8 + w*528 + fb, hreg);
    }
    bar_lds();

#pragma unroll 1
    for (int l = 0; l < 2; ++l) {
      // per-layer biases + dequant multipliers -> registers (nothing in flight here)
      const float* bq_ = ipb + l*1536 + fq;
      const float biq0 = bq_[0],    biq1 = bq_[256];
      const float bik0 = bq_[512],  bik1 = bq_[768];
      const float biv0 = bq_[1024], biv1 = bq_[1280];
      const float aob0 = aob[l*512 + fq], aob1 = aob[l*512 + 256 + fq];
      const float ffb0 = ffb[l*512 + fq], ffb1 = ffb[l*512 + 256 + fq];
      const float* sip = scl + l*1536;
      const float mq0 = sip[fq]       * (1.f/32.f), mq1 = sip[256 + fq]  * (1.f/32.f);
      const float mk0 = sip[512 + fq] * (1.f/32.f), mk1 = sip[768 + fq]  * (1.f/32.f);
      const float mv0 = sip[1024+ fq] * (1.f/32.f), mv1 = sip[1280 + fq] * (1.f/32.f);
      const float* swo = scl + 3072 + l*512;
      const float mo0 = swo[fq] * (1.f/32.f), mo1 = swo[256 + fq] * (1.f/32.f);
      const float* swf = scl + 4096 + l*512;
      const float mf0 = swf[fq] * (1.f/32.f), mf1 = swf[256 + fq] * (1.f/32.f);

      const u8* wiL = win8 + (size_t)l*786432;
      const u8* woL = wo8 + (size_t)l*262144;
      const u8* wfL = wf8 + (size_t)l*262144;

      int4v oacc0 = {0,0,0,0}, oacc1 = oacc0;

#pragma unroll 1
      for (int pass = 0; pass < 2; ++pass) {
        const int hl = w >> 2;
        const int dhb = (w & 3) * 16;

        // ---- QKV GEMM (i8): K=512, 8 chunks x 3 streams, depth-4 pipeline ----
        {
          const u8* A8 = h_i8 + c*528 + g*16;
          const u8* uq = wiL + (size_t)pass*131072;  // block-uniform bases
          const u8* uk = uq + 262144;
          const u8* uv = uq + 524288;
          int4v aq = {0,0,0,0}, ak = aq, av = aq;
          int4v Bq[4], Bk[4], Bv[4];
          GLV(Bq[0], uq, vofs[0]); GLV(Bk[0], uk, vofs[0]); GLV(Bv[0], uv, vofs[0]);
          GLV(Bq[1], uq, vofs[1]); GLV(Bk[1], uk, vofs[1]); GLV(Bv[1], uv, vofs[1]);
          GLV(Bq[2], uq, vofs[2]); GLV(Bk[2], uk, vofs[2]); GLV(Bv[2], uv, vofs[2]);
          GLV(Bq[3], uq, vofs[3]); GLV(Bk[3], uk, vofs[3]); GLV(Bv[3], uv, vofs[3]);

#define QKV_STEP(kt2, nq, nk, nv) { \
            int4v a = *(const int4v*)(A8 + (kt2)*64); \
            WVX(Bq[(kt2)&3], nq); aq = MFMAI8(a, Bq[(kt2)&3], aq); \
            WVX(Bk[(kt2)&3], nk); ak = MFMAI8(a, Bk[(kt2)&3], ak); \
            WVX(Bv[(kt2)&3], nv); av = MFMAI8(a, Bv[(kt2)&3], av); \
            if ((kt2) < 4) { \
              GLV(Bq[(kt2)&3], uq, vofs[(kt2)+4]); \
              GLV(Bk[(kt2)&3], uk, vofs[(kt2)+4]); \
              GLV(Bv[(kt2)&3], uv, vofs[(kt2)+4]); \
            } }
          QKV_STEP(0, 11, 10, 9)
          QKV_STEP(1, 11, 10, 9)
          QKV_STEP(2, 11, 10, 9)
          QKV_STEP(3, 11, 10, 9)
          QKV_STEP(4, 11, 10, 9)
          QKV_STEP(5,  8,  7, 6)
          QKV_STEP(6,  5,  4, 3)
          QKV_STEP(7,  2,  1, 0)

          const float biq = pass ? biq1 : biq0;
          const float bik = pass ? bik1 : bik0;
          const float biv = pass ? biv1 : biv0;
          const float mq = pass ? mq1 : mq0;
          const float mk = pass ? mk1 : mk0;
          const float mv = pass ? mv1 : mv0;
#pragma unroll
          for (int r = 0; r < 4; ++r) {
            int tok = 4*g + r;
            q_lds[hl*1152 + tok*72 + dhb + c] = f2bf((float)aq[r]*mq + biq);
            k_lds[hl*1152 + tok*72 + dhb + c] = f2bf((float)ak[r]*mk + bik);
            vbuf[hl*2560 + (dhb + c)*40 + tok] = f2bf((float)av[r]*mv + biv);
          }
        }
        bar_lds();

        // ---- out-proj weights (i8): 8 loads, in flight through softmax+PV ----
        int4v O0[4], O1[4];
        {
          const u8* uo0 = woL + pass*4096;      // uniform (chunks pass*4..pass*4+3)
          const u8* uo1 = uo0 + 131072;         // tile w+16
          GLV(O0[0], uo0, vofs[0]); GLV(O1[0], uo1, vofs[0]);
          GLV(O0[1], uo0, vofs[1]); GLV(O1[1], uo1, vofs[1]);
          GLV(O0[2], uo0, vofs[2]); GLV(O1[2], uo1, vofs[2]);
          GLV(O0[3], uo0, vofs[3]); GLV(O1[3], uo1, vofs[3]);
        }

        // ---- scores + masked softmax (bf16): waves 0..3 ----
        if (w < 4) {
          f32x4 sc = {0.f,0.f,0.f,0.f};
#pragma unroll
          for (int k2 = 0; k2 < 2; ++k2) {
            short8 qa = *(const short8*)&q_lds[w*1152 + c*72 + k2*32 + g*8];
            short8 kb = *(const short8*)&k_lds[w*1152 + c*72 + k2*32 + g*8];
            sc = MFMA(qa, kb, sc, 0,0,0);
          }
          float sv[4], mx[4], ex[4], sm[4];
#pragma unroll
          for (int r = 0; r < 4; ++r) {
            int row = 4*g + r;
            bool msk = ((c > cic) || (row > cic)) && (c != 0);
            sv[r] = msk ? NEGV : sc[r]*0.125f;
            mx[r] = sv[r];
          }
#pragma unroll
          for (int r = 0; r < 4; ++r) {
            mx[r] = fmaxf(mx[r], __shfl_xor(mx[r], 1));
            mx[r] = fmaxf(mx[r], __shfl_xor(mx[r], 2));
            mx[r] = fmaxf(mx[r], __shfl_xor(mx[r], 4));
            mx[r] = fmaxf(mx[r], __shfl_xor(mx[r], 8));
          }
#pragma unroll
          for (int r = 0; r < 4; ++r) { ex[r] = __expf(sv[r] - mx[r]); sm[r] = ex[r]; }
#pragma unroll
          for (int r = 0; r < 4; ++r) {
            sm[r] += __shfl_xor(sm[r], 1);
            sm[r] += __shfl_xor(sm[r], 2);
            sm[r] += __shfl_xor(sm[r], 4);
            sm[r] += __shfl_xor(sm[r], 8);
          }
#pragma unroll
          for (int r = 0; r < 4; ++r)
            p_lds[w*640 + (4*g + r)*40 + c] = f2bf(ex[r] / sm[r]);
        }
        bar_lds();

        // ---- PV (bf16) -> abuf int8 (x32) ----
        {
          const int hl2 = w >> 2, ct = w & 3;
          short8 pa = *(const short8*)&p_lds[hl2*640 + c*40 + g*8];
          short8 vb = *(const short8*)&vbuf[hl2*2560 + (ct*16 + c)*40 + g*8];
          f32x4 ov = {0.f,0.f,0.f,0.f};
          ov = MFMA(pa, vb, ov, 0,0,0);
#pragma unroll
          for (int r = 0; r < 4; ++r)
            abuf_i8[(4*g + r)*272 + hl2*64 + ct*16 + c] = (u8)(q8(ov[r]*32.f) & 0xff);
        }
        bar_lds();

        // ---- out-proj partial (i8), K=256 ----
        {
          const u8* A8o = abuf_i8 + c*272 + g*16;
#define OP_STEP(kt2, n0, n1) { \
            int4v a = *(const int4v*)(A8o + (kt2)*64); \
            WVX(O0[kt2], n0); oacc0 = MFMAI8(a, O0[kt2], oacc0); \
            WVX(O1[kt2], n1); oacc1 = MFMAI8(a, O1[kt2], oacc1); }
          OP_STEP(0, 7, 6)
          OP_STEP(1, 5, 4)
          OP_STEP(2, 3, 2)
          OP_STEP(3, 1, 0)
        }
        bar_lds();
      } // pass

      // ---- write out-proj result (dequant + attn-out bias) ----
#pragma unroll
      for (int r = 0; r < 4; ++r) {
        dbuf[(4*g + r)*520 + fq]       = f2bf((float)oacc0[r]*mo0 + aob0);
        dbuf[(4*g + r)*520 + 256 + fq] = f2bf((float)oacc1[r]*mo1 + aob1);
      }
      bar_lds();

      // ---- FF weight prologue (i8, 8 loads), hides behind LN1 ----
      int4v F0[4], F1[4];
      const u8* uf0 = wfL;
      const u8* uf1 = wfL + 131072;
      GLV(F0[0], uf0, vofs[0]); GLV(F1[0], uf1, vofs[0]);
      GLV(F0[1], uf0, vofs[1]); GLV(F1[1], uf1, vofs[1]);
      GLV(F0[2], uf0, vofs[2]); GLV(F1[2], uf1, vofs[2]);
      GLV(F0[3], uf0, vofs[3]); GLV(F1[3], uf1, vofs[3]);

      // ---- residual + LN1 (params from LDS) ----
      {
        const ushort_t* lpS = lnp + l*2048;
        const ushort_t* lpB = lnp + l*2048 + 512;
        float sum = 0.f;
#pragma unroll
        for (int j = 0; j < 8; ++j) {
          hreg[j] += bf2f(dbuf[w*520 + fb + j]);
          sum += hreg[j];
        }
        sum += __shfl_xor(sum, 1); sum += __shfl_xor(sum, 2); sum += __shfl_xor(sum, 4);
        sum += __shfl_xor(sum, 8); sum += __shfl_xor(sum, 16); sum += __shfl_xor(sum, 32);
        float mu = sum * (1.0f/512.0f);
        float s2 = 0.f;
#pragma unroll
        for (int j = 0; j < 8; ++j) { float dd = hreg[j] - mu; s2 += dd*dd; }
        s2 += __shfl_xor(s2, 1); s2 += __shfl_xor(s2, 2); s2 += __shfl_xor(s2, 4);
        s2 += __shfl_xor(s2, 8); s2 += __shfl_xor(s2, 16); s2 += __shfl_xor(s2, 32);
        float rs = rsqrtf(s2 * (1.0f/512.0f) + EPSV);
#pragma unroll
        for (int j = 0; j < 8; ++j)
          hreg[j] = (hreg[j] - mu) * rs * bf2f(lpS[fb + j]) + bf2f(lpB[fb + j]);
        quant8_store(h_i8 + w*528 + fb, hreg);
      }
      bar_lds();

      // ---- FF GEMM (i8): K=512, forced pipeline ----
      {
        int4v f0 = {0,0,0,0}, f1 = f0;
        const u8* A8 = h_i8 + c*528 + g*16;
#define FF_STEP(kt2, n0, n1) { \
          int4v a = *(const int4v*)(A8 + (kt2)*64); \
          WVX(F0[(kt2)&3], n0); f0 = MFMAI8(a, F0[(kt2)&3], f0); \
          WVX(F1[(kt2)&3], n1); f1 = MFMAI8(a, F1[(kt2)&3], f1); \
          if ((kt2) < 4) { \
            GLV(F0[(kt2)&3], uf0, vofs[(kt2)+4]); \
            GLV(F1[(kt2)&3], uf1, vofs[(kt2)+4]); \
          } }
        FF_STEP(0, 7, 6)
        FF_STEP(1, 7, 6)
        FF_STEP(2, 7, 6)
        FF_STEP(3, 7, 6)
        FF_STEP(4, 7, 6)
        FF_STEP(5, 5, 4)
        FF_STEP(6, 3, 2)
        FF_STEP(7, 1, 0)
        bar_lds();
#pragma unroll
        for (int r = 0; r < 4; ++r) {
          dbuf[(4*g + r)*520 + fq]       = f2bf((float)f0[r]*mf0 + ffb0);
          dbuf[(4*g + r)*520 + 256 + fq] = f2bf((float)f1[r]*mf1 + ffb1);
        }
      }
      bar_lds();

      // ---- residual + LN2 ----
      {
        const ushort_t* lpS = lnp + l*2048 + 1024;
        const ushort_t* lpB = lnp + l*2048 + 1536;
        float sum = 0.f;
#pragma unroll
        for (int j = 0; j < 8; ++j) {
          hreg[j] += bf2f(dbuf[w*520 + fb + j]);
          sum += hreg[j];
        }
        sum += __shfl_xor(sum, 1); sum += __shfl_xor(sum, 2); sum += __shfl_xor(sum, 4);
        sum += __shfl_xor(sum, 8); sum += __shfl_xor(sum, 16); sum += __shfl_xor(sum, 32);
        float mu = sum * (1.0f/512.0f);
        float s2 = 0.f;
#pragma unroll
        for (int j = 0; j < 8; ++j) { float dd = hreg[j] - mu; s2 += dd*dd; }
        s2 += __shfl_xor(s2, 1); s2 += __shfl_xor(s2, 2); s2 += __shfl_xor(s2, 4);
        s2 += __shfl_xor(s2, 8); s2 += __shfl_xor(s2, 16); s2 += __shfl_xor(s2, 32);
        float rs = rsqrtf(s2 * (1.0f/512.0f) + EPSV);
#pragma unroll
        for (int j = 0; j < 8; ++j)
          hreg[j] = (hreg[j] - mu) * rs * bf2f(lpS[fb + j]) + bf2f(lpB[fb + j]);
        quant8_store(h_i8 + w*528 + fb, hreg);
      }
      bar_lds();
    } // layer

    // ---- output projection (i8): out_t = h[cic] @ Wout^T + b_out ----
    if (w < 8) {
      const int crow = (cic < 15) ? cic : 15;
      const u8* A8 = h_i8 + c*528 + g*16;
      int4v WB[8];
      GLV(WB[0], wout8, vofs[0]); GLV(WB[1], wout8, vofs[1]);
      GLV(WB[2], wout8, vofs[2]); GLV(WB[3], wout8, vofs[3]);
      GLV(WB[4], wout8, vofs[4]); GLV(WB[5], wout8, vofs[5]);
      GLV(WB[6], wout8, vofs[6]); GLV(WB[7], wout8, vofs[7]);
      int4v oo = {0,0,0,0};
#define WOUT_STEP(kt2, n) { \
        int4v a = *(const int4v*)(A8 + (kt2)*64); \
        WVX(WB[kt2], n); oo = MFMAI8(a, WB[kt2], oo); }
      WOUT_STEP(0, 7)
      WOUT_STEP(1, 6)
      WOUT_STEP(2, 5)
      WOUT_STEP(3, 4)
      WOUT_STEP(4, 3)
      WOUT_STEP(5, 2)
      WOUT_STEP(6, 1)
      WOUT_STEP(7, 0)
      if (g == (crow >> 2)) {
        int r = crow & 3;
        int val = (r == 0) ? oo[0] : (r == 1) ? oo[1] : (r == 2) ? oo[2] : oo[3];
        out[((size_t)t*BB + b)*OUTD + w*16 + c] = (float)val * mw + boutr;
      }
    }
    bar_lds();
  } // t

  // ---- epilogue: new_h = [h_fin, pad, ci+16] ----
  const size_t OB = (size_t)SS * BB * OUTD;
#pragma unroll
  for (int j = 0; j < 8; ++j)
    out[OB + hsb + (size_t)w*E + fb + j] = hreg[j];
  for (int i = th; i < 48*512; i += 1024)
    out[OB + hsb + 8192 + i] = hstate[hsb + 8192 + i];
  if (th == 0) out[OB + hsb + 32768] = (float)(ci0 + SS);
}

// ---------------- launcher ----------------
extern "C" void kernel_launch(void* const* d_in, const int* in_sizes, int n_in,
                              void* d_out, int out_size, void* d_ws, size_t ws_size,
                              hipStream_t stream) {
  const float* seq  = (const float*)d_in[0];
  const float* hs   = (const float*)d_in[1];
  const float* Win  = (const float*)d_in[2];
  const float* b_in = (const float*)d_in[3];
  const float* Wout = (const float*)d_in[4];
  const float* bo   = (const float*)d_in[5];
  const float* ipw  = (const float*)d_in[6];
  const float* ipb  = (const float*)d_in[7];
  const float* aow  = (const float*)d_in[8];
  const float* aob  = (const float*)d_in[9];
  const float* l1s  = (const float*)d_in[10];
  const float* l1b  = (const float*)d_in[11];
  const float* l2s  = (const float*)d_in[12];
  const float* l2b  = (const float*)d_in[13];
  const float* ffw  = (const float*)d_in[14];
  const float* ffb  = (const float*)d_in[15];

  char* ws = (char*)d_ws;
  u8*    win8  = (u8*)   (ws + 0);          // 1,572,864 B
  u8*    wo8   = (u8*)   (ws + 1572864);    //   524,288 B
  u8*    wf8   = (u8*)   (ws + 2097152);    //   524,288 B
  u8*    wout8 = (u8*)   (ws + 2621440);    //    65,536 B
  float* scl   = (float*)(ws + 2686976);    //    20,992 B (5248 f32)
  float* winT  = (float*)(ws + 2707968);    //   524,288 B
  float* X     = (float*)(ws + 3232256);    // 4,194,304 B

  wscale_kernel<<<21, 256, 0, stream>>>(ipw, aow, ffw, Wout, scl);
  wconvert_kernel<<<512, 256, 0, stream>>>(ipw, aow, ffw, Wout, Win, scl,
                                           win8, wo8, wf8, wout8, winT);
  xproj_kernel<<<BB, 512, 0, stream>>>(seq, winT, b_in, X);
  encoder_kernel<<<BB, 1024, 0, stream>>>(X, hs, win8, wo8, wf8, wout8, scl,
                                          ipb, aob, l1s, l1b, l2s, l2b, ffb, bo,
                                          (float*)d_out);
}